// Round 6
// baseline (33024.652 us; speedup 1.0000x reference)
//
#include <hip/hip_runtime.h>
#include <stdint.h>

// ---------------------------------------------------------------------------
// 2-layer BiLSTM LM: emb -> BiLSTM(E=256->H=512) -> BiLSTM(1024->512) -> proj
// V=128 E=256 H=512 B=128 T=512.
//
// Round 6: remove ALL per-step cache-maintenance + ALL per-step syncthreads.
// (r4/r5 both ~23us/step with every pipe <4%: the shared cost was the
// agent-scope RELEASE in the arrival atomic -> buffer_wbl2 (full L2
// writeback) per step per WG, plus a 40-64-syncthreads LDS K-loop at
// 1 wave/SIMD.)
//  - h is sc1 (LLC-coherent) => RELAXED publish after __syncthreads vmcnt
//    drain is sufficient; no wbl2/inv in the step loop at all.
//  - W repacked in MFMA-fragment order (1KB/frag coalesced); B-fragments
//    loaded straight to VGPR; 4-tile register pipeline; no LDS, no syncs.
//  - step split: x-part (no h dependency, biases folded in) computed for
//    step s+1 in the barrier-wait shadow; only h-part (16 tiles) on the
//    critical path.
//  - proj (L1, 8 chunks) unchanged except barriers: relaxed publish +
//    ACQUIRE (buffer_inv) only on the pre-proj spin (ring is plain-read).
//
// Numerics (validated r1/r5, absmax 1.95e-3): bf16 MFMA fp32-accum; c f32;
// h carried hi/lo bf16 packed in u32, W k-interleaved dup (k>>1).
// ---------------------------------------------------------------------------

#define TT 512
#define BB 128
#define HH 512
#define VV 128

typedef __attribute__((ext_vector_type(8))) short bf16x8;
typedef __attribute__((ext_vector_type(4))) float f32x4;

#define AGENT __HIP_MEMORY_SCOPE_AGENT

__device__ __forceinline__ ushort f2bf(float f) {
  uint32_t u = __builtin_bit_cast(uint32_t, f);
  u += 0x7FFFu + ((u >> 16) & 1u);
  return (ushort)(u >> 16);
}
__device__ __forceinline__ float bf2f(ushort h) {
  uint32_t u = ((uint32_t)h) << 16;
  return __builtin_bit_cast(float, u);
}
__device__ __forceinline__ float sigm(float x) { return 1.f / (1.f + __expf(-x)); }
__device__ __forceinline__ float tanh_f(float x) { return 1.f - 2.f / (__expf(2.f * x) + 1.f); }

struct TileB { uint4 b0, b1, b2, b3, b4, b5, b6, b7; };
struct TileA { uint4 a0, a1; };

__global__ __launch_bounds__(256) void report_ws(float* __restrict__ out, int n, float val) {
  int i = blockIdx.x * 256 + threadIdx.x;
  if (i < n) out[i] = val;
}

__global__ __launch_bounds__(256) void pack_emb(const float* __restrict__ emb,
                                                ushort* __restrict__ embB) {
  int i = blockIdx.x * 256 + threadIdx.x;  // 32768
  embB[i] = f2bf(emb[i]);
}

// W packed in MFMA-fragment order:
// Wp[((d*32+ub)*KT + kt)*4096 + (ks*4+n)*512 + l*8 + e] =
//   W[n*512 + ub*16 + (l&15)][ kt*64 + ks*32 + (l>>4)*8 + e ]
// where k<1024 -> Whh col k>>1 (hi/lo interleave dup), else Wih col k-1024.
__global__ __launch_bounds__(256) void pack_w(const float* __restrict__ Whh,
                                              const float* __restrict__ Wih,
                                              ushort* __restrict__ Wp,
                                              int KT, int Ein) {
  size_t idx = (size_t)blockIdx.x * 256 + threadIdx.x;
  size_t total = (size_t)2 * 32 * KT * 4096;
  if (idx >= total) return;
  int w = (int)(idx & 4095);
  int e = w & 7, l = (w >> 3) & 63, fr = w >> 9;
  int ks = fr >> 2, n = fr & 3;
  size_t blk = idx >> 12;
  int kt = (int)(blk % KT);
  int ubd = (int)(blk / KT);
  int ub = ubd & 31, d = ubd >> 5;
  int row = n * HH + ub * 16 + (l & 15);
  int k = kt * 64 + ks * 32 + (l >> 4) * 8 + e;
  float val;
  if (k < 1024) val = Whh[((size_t)d * 2048 + row) * HH + (k >> 1)];
  else          val = Wih[((size_t)d * 2048 + row) * Ein + (k - 1024)];
  Wp[idx] = f2bf(val);
}

__global__ __launch_bounds__(256) void pack_wout(const float* __restrict__ Wo,
                                                 ushort* __restrict__ WoB) {
  int i = blockIdx.x * 256 + threadIdx.x;  // 131072
  WoB[i] = f2bf(Wo[i]);
}

// zero parity-0 h buffer (512KB) + barrier counters
__global__ __launch_bounds__(256) void zero_h(unsigned int* __restrict__ hpk,
                                              unsigned int* __restrict__ bars) {
  int i = blockIdx.x * 256 + threadIdx.x;
  ((uint4*)hpk)[i] = make_uint4(0, 0, 0, 0);
  if (i < 96) bars[i] = 0;
}

// ---------------------------------------------------------------------------
// Projection chunk body (layer-1, all 128 WGs; validated r5).
// ---------------------------------------------------------------------------
__device__ void proj_body(int k, int wg, int tid, const ushort* __restrict__ ring,
                          const ushort* __restrict__ WoB, const float* __restrict__ bout,
                          float* __restrict__ out, char* smem) {
  const int slot = wg & 63;
  const int dirp = wg >> 6;
  const int tp = (dirp ? (448 - 64 * k) : (64 * k)) + slot;
  const int mode = (k >= 4);
  ushort* As = (ushort*)smem;
  ushort* Bs = (ushort*)(smem + 16384);
  const int wm = tid >> 6;
  const int lane = tid & 63;

  f32x4 acc[2][8] = {};

  for (int kt = 0; kt < 8; ++kt) {  // K = 512
    const int kel0 = kt * 64;
    uint4 ra[4], rb[4];
#pragma unroll
    for (int it = 0; it < 4; ++it) {
      int c = it * 256 + tid;
      int r = c >> 3;
      int bq = c & 7;
      ra[it] = *(const uint4*)(ring + ((size_t)(dirp * 64 + slot) * BB + r) * HH + kel0 + bq * 8);
      rb[it] = *(const uint4*)(WoB + (size_t)r * 1024 + dirp * HH + kel0 + bq * 8);
    }
    __syncthreads();
#pragma unroll
    for (int it = 0; it < 4; ++it) {
      int c = it * 256 + tid;
      int r = c >> 3;
      int bq = c & 7;
      int off = r * 128 + ((bq << 4) ^ ((r & 7) << 4));
      *(uint4*)((char*)As + off) = ra[it];
      *(uint4*)((char*)Bs + off) = rb[it];
    }
    __syncthreads();
#pragma unroll
    for (int ks = 0; ks < 2; ++ks) {
      const int kbyte = (ks * 32 + ((lane >> 4) << 3)) << 1;
      bf16x8 a[2], bb[8];
#pragma unroll
      for (int m = 0; m < 2; ++m) {
        int row = wm * 32 + m * 16 + (lane & 15);
        a[m] = *(const bf16x8*)((const char*)As + row * 128 + (kbyte ^ ((row & 7) << 4)));
      }
#pragma unroll
      for (int n = 0; n < 8; ++n) {
        int row = n * 16 + (lane & 15);
        bb[n] = *(const bf16x8*)((const char*)Bs + row * 128 + (kbyte ^ ((row & 7) << 4)));
      }
#pragma unroll
      for (int m = 0; m < 2; ++m)
#pragma unroll
        for (int n = 0; n < 8; ++n)
          acc[m][n] = __builtin_amdgcn_mfma_f32_16x16x32_bf16(a[m], bb[n], acc[m][n], 0, 0, 0);
    }
  }

  const int rbase = ((tid & 63) >> 4) * 4;
#pragma unroll
  for (int n = 0; n < 8; ++n) {
    int v = n * 16 + (tid & 15);
    float bo = bout[v];
#pragma unroll
    for (int m = 0; m < 2; ++m)
#pragma unroll
      for (int r = 0; r < 4; ++r) {
        int b = (tid >> 6) * 32 + m * 16 + rbase + r;
        size_t o = ((size_t)b * TT + tp) * VV + v;
        if (mode) (void)unsafeAtomicAdd(&out[o], acc[m][n][r]);
        else      __hip_atomic_store(&out[o], acc[m][n][r] + bo, __ATOMIC_RELAXED, AGENT);
      }
  }
}

// ---------------------------------------------------------------------------
// Persistent LSTM layer. grid = 128 WGs = (dir 2)(mh 2)(ub 32), block 256.
// Per step per WG: gates[64 b x 64 rows]; x-part precomputed in the barrier
// shadow, h-part (16 tiles) + epilogue + relaxed publish on critical path.
// No LDS, no syncthreads in the K path; 4-tile register pipeline.
// ---------------------------------------------------------------------------
template <int L0, int XT>
__global__ __launch_bounds__(256, 1) void lstm_persist(
    const ushort* __restrict__ Wp,     // [2][32][KT][8 frag][512] frag-packed
    const ushort* __restrict__ xin,    // L1: h0 [T][B][1024]
    const int* __restrict__ sent,      // L0: [B][T]
    const ushort* __restrict__ embB,   // L0: [128][256]
    unsigned int* __restrict__ hpk,    // [2 par][2 dir][BB][512] u32(hi|lo)
    ushort* __restrict__ hseq,         // L0 out: [T][B][1024]
    ushort* __restrict__ ring,         // L1 out: [2][64][B][512]
    const ushort* __restrict__ WoB,
    const float* __restrict__ bout,
    float* __restrict__ out,
    const float* __restrict__ bih, const float* __restrict__ bhh,
    unsigned int* __restrict__ bars) {
  const int wg = blockIdx.x;
  const int ub = wg & 31, mh = (wg >> 5) & 1, dir = wg >> 6;
  const int tid = threadIdx.x, wm = tid >> 6, lane = tid & 63;
  const int PARW = 2 * BB * 512;
  constexpr int KT = 16 + XT;

  __shared__ __align__(16) char smem[32768];  // proj only

  const ushort* wbase = Wp + (size_t)(dir * 32 + ub) * KT * 4096;

  const int j = ub * 16 + (lane & 15);
  const float b_i = bih[dir * 2048 + j] + bhh[dir * 2048 + j];
  const float b_f = bih[dir * 2048 + HH + j] + bhh[dir * 2048 + HH + j];
  const float b_g = bih[dir * 2048 + 2 * HH + j] + bhh[dir * 2048 + 2 * HH + j];
  const float b_o = bih[dir * 2048 + 3 * HH + j] + bhh[dir * 2048 + 3 * HH + j];
  const int rbase = (lane >> 4) * 4;
  const int arow = mh * 64 + wm * 16 + (lane & 15);
  const size_t hrowu64 = (size_t)(dir * BB + arow) * 256;
  const int ksub = lane >> 4;

  f32x4 cr = {0.f, 0.f, 0.f, 0.f};
  unsigned int* cnt_step = bars + dir * 32;
  unsigned int* cnt_proj = bars + 64;
  unsigned int gcount = 0;

  f32x4 acc0, acc1, acc2, acc3;

  auto bc = [](uint4 u) { return __builtin_bit_cast(bf16x8, u); };

  auto mf = [&](const TileB& B, const TileA& A) {
    bf16x8 a0 = __builtin_bit_cast(bf16x8, A.a0);
    bf16x8 a1 = __builtin_bit_cast(bf16x8, A.a1);
    acc0 = __builtin_amdgcn_mfma_f32_16x16x32_bf16(a0, bc(B.b0), acc0, 0, 0, 0);
    acc1 = __builtin_amdgcn_mfma_f32_16x16x32_bf16(a0, bc(B.b1), acc1, 0, 0, 0);
    acc2 = __builtin_amdgcn_mfma_f32_16x16x32_bf16(a0, bc(B.b2), acc2, 0, 0, 0);
    acc3 = __builtin_amdgcn_mfma_f32_16x16x32_bf16(a0, bc(B.b3), acc3, 0, 0, 0);
    acc0 = __builtin_amdgcn_mfma_f32_16x16x32_bf16(a1, bc(B.b4), acc0, 0, 0, 0);
    acc1 = __builtin_amdgcn_mfma_f32_16x16x32_bf16(a1, bc(B.b5), acc1, 0, 0, 0);
    acc2 = __builtin_amdgcn_mfma_f32_16x16x32_bf16(a1, bc(B.b6), acc2, 0, 0, 0);
    acc3 = __builtin_amdgcn_mfma_f32_16x16x32_bf16(a1, bc(B.b7), acc3, 0, 0, 0);
  };

  auto ldB = [&](int kt) -> TileB {
    const char* p = (const char*)wbase + ((size_t)kt << 13) + (lane << 4);
    TileB t;
    t.b0 = *(const uint4*)(p);
    t.b1 = *(const uint4*)(p + 1024);
    t.b2 = *(const uint4*)(p + 2048);
    t.b3 = *(const uint4*)(p + 3072);
    t.b4 = *(const uint4*)(p + 4096);
    t.b5 = *(const uint4*)(p + 5120);
    t.b6 = *(const uint4*)(p + 6144);
    t.b7 = *(const uint4*)(p + 7168);
    return t;
  };

  auto ldAh = [&](unsigned long long* hin64, int kt) -> TileA {
    unsigned long long* p = hin64 + hrowu64 + (size_t)kt * 16 + ksub * 2;
    unsigned long long x0 = __hip_atomic_load(p + 0, __ATOMIC_RELAXED, AGENT);
    unsigned long long x1 = __hip_atomic_load(p + 1, __ATOMIC_RELAXED, AGENT);
    unsigned long long y0 = __hip_atomic_load(p + 8, __ATOMIC_RELAXED, AGENT);
    unsigned long long y1 = __hip_atomic_load(p + 9, __ATOMIC_RELAXED, AGENT);
    TileA t;
    t.a0 = make_uint4((uint32_t)x0, (uint32_t)(x0 >> 32), (uint32_t)x1, (uint32_t)(x1 >> 32));
    t.a1 = make_uint4((uint32_t)y0, (uint32_t)(y0 >> 32), (uint32_t)y1, (uint32_t)(y1 >> 32));
    return t;
  };

  auto ldAx = [&](const ushort* xrow, int xkt) -> TileA {
    const ushort* p = xrow + xkt * 64 + ksub * 8;
    TileA t;
    t.a0 = *(const uint4*)p;
    t.a1 = *(const uint4*)(p + 32);
    return t;
  };

  // x-part for step with time index t: acc = bias + x(t) @ Wih^T
  auto x_phase = [&](int t) {
    acc0 = (f32x4){b_i, b_i, b_i, b_i};
    acc1 = (f32x4){b_f, b_f, b_f, b_f};
    acc2 = (f32x4){b_g, b_g, b_g, b_g};
    acc3 = (f32x4){b_o, b_o, b_o, b_o};
    const ushort* xrow;
    if constexpr (L0) xrow = embB + sent[arow * TT + t] * 256;
    else              xrow = xin + ((size_t)t * BB + arow) * 1024;
    TileB B0 = ldB(16 + 0), B1 = ldB(16 + 1), B2 = ldB(16 + 2), B3 = ldB(16 + 3);
    TileA A0 = ldAx(xrow, 0), A1 = ldAx(xrow, 1), A2 = ldAx(xrow, 2), A3 = ldAx(xrow, 3);
    if constexpr (XT == 4) {
      mf(B0, A0); mf(B1, A1); mf(B2, A2); mf(B3, A3);
    } else {
#pragma unroll
      for (int g = 0; g < XT / 4 - 1; ++g) {
        mf(B0, A0); B0 = ldB(16 + g * 4 + 4); A0 = ldAx(xrow, g * 4 + 4);
        mf(B1, A1); B1 = ldB(16 + g * 4 + 5); A1 = ldAx(xrow, g * 4 + 5);
        mf(B2, A2); B2 = ldB(16 + g * 4 + 6); A2 = ldAx(xrow, g * 4 + 6);
        mf(B3, A3); B3 = ldB(16 + g * 4 + 7); A3 = ldAx(xrow, g * 4 + 7);
      }
      mf(B0, A0); mf(B1, A1); mf(B2, A2); mf(B3, A3);
    }
  };

  // h-part: acc += h(par) @ Whh^T  (16 tiles)
  auto h_phase = [&](int par) {
    unsigned long long* hin64 = (unsigned long long*)(hpk + (size_t)par * PARW);
    TileB B0 = ldB(0), B1 = ldB(1), B2 = ldB(2), B3 = ldB(3);
    TileA A0 = ldAh(hin64, 0), A1 = ldAh(hin64, 1), A2 = ldAh(hin64, 2), A3 = ldAh(hin64, 3);
#pragma unroll
    for (int g = 0; g < 3; ++g) {
      mf(B0, A0); B0 = ldB(g * 4 + 4); A0 = ldAh(hin64, g * 4 + 4);
      mf(B1, A1); B1 = ldB(g * 4 + 5); A1 = ldAh(hin64, g * 4 + 5);
      mf(B2, A2); B2 = ldB(g * 4 + 6); A2 = ldAh(hin64, g * 4 + 6);
      mf(B3, A3); B3 = ldB(g * 4 + 7); A3 = ldAh(hin64, g * 4 + 7);
    }
    mf(B0, A0); mf(B1, A1); mf(B2, A2); mf(B3, A3);
  };

  // prologue: x-part for step 0
  x_phase(dir ? TT - 1 : 0);

  for (int s = 0; s < TT; ++s) {
    const int t = dir ? (TT - 1 - s) : s;

    // wait for h(s) (relaxed spin; h goes via LLC, no cache maintenance)
    if (tid == 0) {
      while (__hip_atomic_load(cnt_step, __ATOMIC_RELAXED, AGENT) < 64u * (unsigned)s)
        __builtin_amdgcn_s_sleep(1);
    }
    __syncthreads();

    h_phase(s & 1);

    // epilogue: c/h update; h(s+1) stores via sc1
    unsigned int* hw32 = hpk + (size_t)((s & 1) ^ 1) * PARW;
#pragma unroll
    for (int r = 0; r < 4; ++r) {
      const int brow = mh * 64 + wm * 16 + rbase + r;
      float si = sigm(acc0[r]), sf = sigm(acc1[r]);
      float tg = tanh_f(acc2[r]), so = sigm(acc3[r]);
      float c = sf * cr[r] + si * tg;
      cr[r] = c;
      float h = so * tanh_f(c);
      ushort hi = f2bf(h);
      ushort lo = f2bf(h - bf2f(hi));
      __hip_atomic_store(hw32 + (size_t)(dir * BB + brow) * 512 + j,
                         (uint32_t)hi | ((uint32_t)lo << 16), __ATOMIC_RELAXED, AGENT);
      if constexpr (L0)
        hseq[((size_t)t * BB + brow) * 1024 + dir * HH + j] = hi;
      else
        __hip_atomic_store(ring + ((size_t)(dir * 64 + (t & 63)) * BB + brow) * HH + j,
                           hi, __ATOMIC_RELAXED, AGENT);
    }

    __syncthreads();  // drain all waves' stores (vmcnt 0) before publish
    if (tid == 0) {
      __hip_atomic_fetch_add(cnt_step, 1u, __ATOMIC_RELAXED, AGENT);
      if constexpr (!L0) {
        if ((s & 63) == 63)
          __hip_atomic_fetch_add(cnt_proj, 1u, __ATOMIC_RELAXED, AGENT);
      }
    }

    // x-part for step s+1 in the barrier-wait shadow
    if (s + 1 < TT) x_phase(dir ? (TT - 2 - s) : (s + 1));

    if constexpr (!L0) {
      if ((s & 63) == 63) {
        ++gcount;  // pre-proj: all 128 WGs published ring chunk
        if (tid == 0) {
          while (__hip_atomic_load(cnt_proj, __ATOMIC_RELAXED, AGENT) < 128u * gcount)
            __builtin_amdgcn_s_sleep(1);
          (void)__hip_atomic_load(cnt_proj, __ATOMIC_ACQUIRE, AGENT);  // inv: ring plain-read
        }
        __syncthreads();
        proj_body(s >> 6, wg, tid, ring, WoB, bout, out, smem);
        __syncthreads();  // proj reads drained
        ++gcount;          // post-proj: protect ring reuse
        if (tid == 0) {
          __hip_atomic_fetch_add(cnt_proj, 1u, __ATOMIC_RELAXED, AGENT);
          while (__hip_atomic_load(cnt_proj, __ATOMIC_RELAXED, AGENT) < 128u * gcount)
            __builtin_amdgcn_s_sleep(1);
        }
        __syncthreads();
      }
    }
  }
}

// ---------------------------------------------------------------------------
extern "C" void kernel_launch(void* const* d_in, const int* in_sizes, int n_in,
                              void* d_out, int out_size, void* d_ws, size_t ws_size,
                              hipStream_t stream) {
  const int* sent = (const int*)d_in[0];
  const float* emb = (const float*)d_in[1];
  const float* Wih0 = (const float*)d_in[2];
  const float* Whh0 = (const float*)d_in[3];
  const float* bih0 = (const float*)d_in[4];
  const float* bhh0 = (const float*)d_in[5];
  const float* Wih1 = (const float*)d_in[6];
  const float* Whh1 = (const float*)d_in[7];
  const float* bih1 = (const float*)d_in[8];
  const float* bhh1 = (const float*)d_in[9];
  const float* Wout = (const float*)d_in[10];
  const float* bout = (const float*)d_in[11];
  float* out = (float*)d_out;

  const size_t NEED = 179634688;
  if (ws_size < NEED) {
    report_ws<<<(out_size + 255) / 256, 256, 0, stream>>>(out, out_size,
                                                          (float)(ws_size >> 20));
    return;
  }
  char* ws = (char*)d_ws;
  ushort* h0   = (ushort*)(ws + 0);                 // 134,217,728  [T][B][1024]
  ushort* Wp0  = (ushort*)(ws + 134217728);         //  10,485,760  frag-packed KT=20
  ushort* Wp1  = (ushort*)(ws + 144703488);         //  16,777,216  frag-packed KT=32
  ushort* WoB  = (ushort*)(ws + 161480704);         //     262,144
  ushort* embB = (ushort*)(ws + 161742848);         //      65,536
  unsigned int* hpk = (unsigned int*)(ws + 161808384); // 1,048,576 [2][2][B][512] u32
  ushort* ring = (ushort*)(ws + 162856960);         //  16,777,216  [2][64][B][512]
  unsigned int* bars = (unsigned int*)(ws + 179634176);  // 512

  pack_emb<<<128, 256, 0, stream>>>(emb, embB);
  pack_w<<<20480, 256, 0, stream>>>(Whh0, Wih0, Wp0, 20, 256);
  pack_w<<<32768, 256, 0, stream>>>(Whh1, Wih1, Wp1, 32, 1024);
  pack_wout<<<512, 256, 0, stream>>>(Wout, WoB);

  // layer 0
  zero_h<<<128, 256, 0, stream>>>(hpk, bars);
  lstm_persist<1, 4><<<128, 256, 0, stream>>>(
      Wp0, h0, sent, embB, hpk, h0, ring, WoB, bout, out, bih0, bhh0, bars);

  // layer 1 (proj folded in)
  zero_h<<<128, 256, 0, stream>>>(hpk, bars);
  lstm_persist<0, 16><<<128, 256, 0, stream>>>(
      Wp1, h0, sent, embB, hpk, h0, ring, WoB, bout, out, bih1, bhh1, bars);
}

// Round 7
// 23077.151 us; speedup vs baseline: 1.4311x; 1.4311x over previous
//
#include <hip/hip_runtime.h>
#include <stdint.h>

// ---------------------------------------------------------------------------
// 2-layer BiLSTM LM: emb -> BiLSTM(E=256->H=512) -> BiLSTM(1024->512) -> proj
// V=128 E=256 H=512 B=128 T=512.
//
// Round 7: weight-stability + L2-served h.
//  r6 post-mortem: FETCH 17.5GB/dispatch = W re-streamed every step (per-XCD
//  W footprint == L2 size, thrash). r4/r5: per-step RELEASE wrote back L2.
//  - 128 WGs = 2dir x 64nb. WG: M=128(all batch), N=32 (4 gates x 8 units),
//    K=2048 (L1) / 1280 (L0).
//  - Whh-part of W (64KB, frag-packed) preloaded to LDS ONCE: immune to
//    eviction AND to per-step L2 invalidation. x-part W streamed (in shadow).
//  - ALL global writes are sc1/atomic => L2 always clean => per-step
//    consumer ACQUIRE (L2 inv; r6-proj-validated pattern) is cheap, and h
//    reads are PLAIN loads served by L2 broadcast (not LLC atomics).
//  - gate exchange via padded LDS [128][33] f32; c in regs (4/thread).
//  - slot-array barrier (one slot per WG, no atomic contention), relaxed
//    publish after vmcnt drain; x_phase(s+1) in the wait shadow.
//  - proj: BK=32 variant (16KB LDS), same write/add chunk pairing (r6).
//
// Numerics (validated r1..r6, absmax 1.95e-3): bf16 MFMA fp32-accum; c f32;
// h carried hi/lo bf16 packed in u32; W k-interleaved dup (k>>1).
// ---------------------------------------------------------------------------

#define TT 512
#define BB 128
#define HH 512
#define VV 128
#define AGENT __HIP_MEMORY_SCOPE_AGENT

typedef __attribute__((ext_vector_type(8))) short bf16x8;
typedef __attribute__((ext_vector_type(4))) float f32x4;

__device__ __forceinline__ ushort f2bf(float f) {
  uint32_t u = __builtin_bit_cast(uint32_t, f);
  u += 0x7FFFu + ((u >> 16) & 1u);
  return (ushort)(u >> 16);
}
__device__ __forceinline__ float bf2f(ushort h) {
  uint32_t u = ((uint32_t)h) << 16;
  return __builtin_bit_cast(float, u);
}
__device__ __forceinline__ float sigm(float x) { return 1.f / (1.f + __expf(-x)); }
__device__ __forceinline__ float tanh_f(float x) { return 1.f - 2.f / (__expf(2.f * x) + 1.f); }

__global__ __launch_bounds__(256) void report_ws(float* __restrict__ out, int n, float val) {
  int i = blockIdx.x * 256 + threadIdx.x;
  if (i < n) out[i] = val;
}

__global__ __launch_bounds__(256) void pack_emb(const float* __restrict__ emb,
                                                ushort* __restrict__ embB) {
  int i = blockIdx.x * 256 + threadIdx.x;  // 32768
  embB[i] = f2bf(emb[i]);
}

// Frag-packed W for the new partition.
// Slice (d, nb) = 2*KSL frags of 1KB. frag f = kslg*2 + n2:
//   elem (l, e): row_local = n2*16 + (l&15); gate = row_local>>3; uu = row_local&7
//   grow = gate*512 + nb*8 + uu;  k = kslg*32 + (l>>4)*8 + e
//   k<1024 -> Whh[d][grow][k>>1] (hi/lo dup); else Wih[d][grow][k-1024].
__global__ __launch_bounds__(256) void pack_w(const float* __restrict__ Whh,
                                              const float* __restrict__ Wih,
                                              ushort* __restrict__ Wp,
                                              int KSL, int Ein) {
  size_t idx = (size_t)blockIdx.x * 256 + threadIdx.x;
  size_t total = (size_t)128 * 2 * KSL * 512;
  if (idx >= total) return;
  int e = (int)(idx & 7);
  int l = (int)((idx >> 3) & 63);
  int f = (int)((idx >> 9) % (size_t)(2 * KSL));
  int sl = (int)(idx / ((size_t)1024 * KSL));
  int nb = sl & 63, d = sl >> 6;
  int n2 = f & 1, kslg = f >> 1;
  int rloc = n2 * 16 + (l & 15);
  int grow = (rloc >> 3) * 512 + nb * 8 + (rloc & 7);
  int k = kslg * 32 + (l >> 4) * 8 + e;
  float val;
  if (k < 1024) val = Whh[((size_t)d * 2048 + grow) * 512 + (k >> 1)];
  else          val = Wih[((size_t)d * 2048 + grow) * Ein + (k - 1024)];
  Wp[idx] = f2bf(val);
}

__global__ __launch_bounds__(256) void pack_wout(const float* __restrict__ Wo,
                                                 ushort* __restrict__ WoB) {
  int i = blockIdx.x * 256 + threadIdx.x;  // 131072
  WoB[i] = f2bf(Wo[i]);
}

// zero parity-0 h buffer (512KB) + slot arrays (256 u32)
__global__ __launch_bounds__(256) void zero_h(unsigned int* __restrict__ hpk,
                                              unsigned int* __restrict__ bars) {
  int i = blockIdx.x * 256 + threadIdx.x;
  ((uint4*)hpk)[i] = make_uint4(0, 0, 0, 0);
  if (i < 256) bars[i] = 0;
}

// ---------------------------------------------------------------------------
// Projection chunk (layer-1, all 128 WGs). BK=32, 16KB LDS.
// ring read PLAIN (preceded by ACQUIRE-inv); out: atomic store / fadd (r6).
// ---------------------------------------------------------------------------
__device__ void proj_body(int k, int wg, int tid, const ushort* __restrict__ ring,
                          const ushort* __restrict__ WoB, const float* __restrict__ bout,
                          float* __restrict__ out, char* shm) {
  const int slot = wg & 63;
  const int dirp = wg >> 6;
  const int tp = (dirp ? (448 - 64 * k) : (64 * k)) + slot;
  const int mode = (k >= 4);
  ushort* As = (ushort*)shm;            // [128][32] swizzled 64B rows
  ushort* Bs = (ushort*)(shm + 8192);
  const int wm = tid >> 6;
  const int lane = tid & 63;

  f32x4 acc[2][8] = {};

  for (int kt = 0; kt < 16; ++kt) {     // K = 512
    uint4 ra[2], rb[2];
#pragma unroll
    for (int it = 0; it < 2; ++it) {
      int c = it * 256 + tid;
      int r = c >> 2, bq = c & 3;
      ra[it] = *(const uint4*)(ring + ((size_t)(dirp * 64 + slot) * BB + r) * HH + kt * 32 + bq * 8);
      rb[it] = *(const uint4*)(WoB + (size_t)r * 1024 + dirp * HH + kt * 32 + bq * 8);
    }
    __syncthreads();
#pragma unroll
    for (int it = 0; it < 2; ++it) {
      int c = it * 256 + tid;
      int r = c >> 2, bq = c & 3;
      int off = r * 64 + ((bq << 4) ^ ((r & 3) << 4));
      *(uint4*)((char*)As + off) = ra[it];
      *(uint4*)((char*)Bs + off) = rb[it];
    }
    __syncthreads();
    const int kb = (lane >> 4) << 4;
    bf16x8 a[2], bb[8];
#pragma unroll
    for (int m = 0; m < 2; ++m) {
      int row = wm * 32 + m * 16 + (lane & 15);
      a[m] = *(const bf16x8*)((const char*)As + row * 64 + (kb ^ ((row & 3) << 4)));
    }
#pragma unroll
    for (int n = 0; n < 8; ++n) {
      int row = n * 16 + (lane & 15);
      bb[n] = *(const bf16x8*)((const char*)Bs + row * 64 + (kb ^ ((row & 3) << 4)));
    }
#pragma unroll
    for (int m = 0; m < 2; ++m)
#pragma unroll
      for (int n = 0; n < 8; ++n)
        acc[m][n] = __builtin_amdgcn_mfma_f32_16x16x32_bf16(a[m], bb[n], acc[m][n], 0, 0, 0);
  }

  const int rbase = (lane >> 4) * 4;
#pragma unroll
  for (int n = 0; n < 8; ++n) {
    int v = n * 16 + (lane & 15);
    float bo = bout[v];
#pragma unroll
    for (int m = 0; m < 2; ++m)
#pragma unroll
      for (int r = 0; r < 4; ++r) {
        int b = wm * 32 + m * 16 + rbase + r;
        size_t o = ((size_t)b * TT + tp) * VV + v;
        if (mode) (void)unsafeAtomicAdd(&out[o], acc[m][n][r]);
        else      __hip_atomic_store(&out[o], acc[m][n][r] + bo, __ATOMIC_RELAXED, AGENT);
      }
  }
}

// ---------------------------------------------------------------------------
// Persistent LSTM layer. 128 WGs = (dir 2)(nb 64), 256 threads (4 waves).
// Wave w owns batch rows [w*32, w*32+32) (2 m-tiles); N=32 (both n2 tiles).
// h-part W resident in LDS; x-part W streamed; h plain-loaded post-inv.
// ---------------------------------------------------------------------------
template <int IS_L0, int KSLX>
__global__ __launch_bounds__(256, 1) void lstm_persist(
    const ushort* __restrict__ Wp,    // [128 slices][2*KSL frags][512]
    ushort* __restrict__ hseq,        // [T][B][1024]: L0 writes (sc1), L1 reads x
    const int* __restrict__ sent,     // L0: [B][T]
    const ushort* __restrict__ embB,  // L0: [128][256]
    unsigned int* __restrict__ hpk,   // [2 par][2 dir][BB][512] u32 (hi|lo)
    ushort* __restrict__ ring,        // L1: [2][64][B][512]
    const ushort* __restrict__ WoB,   // L1: [V][1024]
    const float* __restrict__ bout,   // L1: [V]
    float* __restrict__ out,          // L1: [B][T][V]
    const float* __restrict__ bih, const float* __restrict__ bhh,
    unsigned int* __restrict__ bars) {
  constexpr int KSL = 32 + KSLX;
  const int wg = blockIdx.x;
  const int nb = wg & 63;
  const int dir = wg >> 6;
  const int tid = threadIdx.x;
  const int wm = tid >> 6;
  const int lane = tid & 63;
  const int PARW = 2 * BB * 512;      // u32 per parity buffer

  __shared__ __align__(16) char smem[65536 + 16896];  // 64KB Whh-frags + region1

  const ushort* wslice = Wp + (size_t)(dir * 64 + nb) * (2 * KSL * 512);

  // ---- preload Whh-part W (first 64KB of slice) into LDS, once
  for (int i = tid; i < 4096; i += 256)
    ((uint4*)smem)[i] = ((const uint4*)wslice)[i];
  __syncthreads();

  const int rowA0 = wm * 32 + (lane & 15);   // A-fragment rows (fixed)
  const int rowA1 = rowA0 + 16;
  const int ksub = lane >> 4;

  // biases: acc-init per lane (by rl), epilogue per (u,lr) ownership
  const int ju = nb * 8 + (lane & 7);
  const float biJ = bih[dir * 2048 + ju] + bhh[dir * 2048 + ju];
  const float bfJ = bih[dir * 2048 + 512 + ju] + bhh[dir * 2048 + 512 + ju];
  const float bgJ = bih[dir * 2048 + 1024 + ju] + bhh[dir * 2048 + 1024 + ju];
  const float boJ = bih[dir * 2048 + 1536 + ju] + bhh[dir * 2048 + 1536 + ju];
  const float bias0 = (lane & 8) ? bfJ : biJ;
  const float bias1 = (lane & 8) ? boJ : bgJ;

  float cst[4] = {0.f, 0.f, 0.f, 0.f};  // c for 4 (u,lr) pairs, fixed ownership

  unsigned int* stepslot = bars;         // [128]
  unsigned int* projslot = bars + 128;   // [128]

  f32x4 a00, a01, a10, a11;

  auto bc8 = [](uint4 u) { return __builtin_bit_cast(bf16x8, u); };

  const ushort* wx = wslice + 32768;     // x-frag base (ushort units)

  auto x_phase = [&](int t) {
    a00 = (f32x4){bias0, bias0, bias0, bias0};
    a01 = (f32x4){bias1, bias1, bias1, bias1};
    a10 = a00; a11 = a01;
    const ushort *xr0, *xr1;
    if constexpr (IS_L0) {
      xr0 = embB + sent[rowA0 * TT + t] * 256 + ksub * 8;
      xr1 = embB + sent[rowA1 * TT + t] * 256 + ksub * 8;
    } else {
      xr0 = hseq + ((size_t)t * BB + rowA0) * 1024 + ksub * 8;
      xr1 = hseq + ((size_t)t * BB + rowA1) * 1024 + ksub * 8;
    }
    const ushort* wxl = wx + lane * 8;
#pragma unroll
    for (int ksl = 0; ksl < KSLX; ++ksl) {
      uint4 u0 = *(const uint4*)(xr0 + ksl * 32);
      uint4 u1 = *(const uint4*)(xr1 + ksl * 32);
      bf16x8 b0 = *(const bf16x8*)(wxl + (ksl * 2 + 0) * 512);
      bf16x8 b1 = *(const bf16x8*)(wxl + (ksl * 2 + 1) * 512);
      a00 = __builtin_amdgcn_mfma_f32_16x16x32_bf16(bc8(u0), b0, a00, 0, 0, 0);
      a01 = __builtin_amdgcn_mfma_f32_16x16x32_bf16(bc8(u0), b1, a01, 0, 0, 0);
      a10 = __builtin_amdgcn_mfma_f32_16x16x32_bf16(bc8(u1), b0, a10, 0, 0, 0);
      a11 = __builtin_amdgcn_mfma_f32_16x16x32_bf16(bc8(u1), b1, a11, 0, 0, 0);
    }
  };

  auto h_phase = [&](int par) {
    const unsigned int* hb = hpk + (size_t)par * PARW;
    const unsigned int* h0p = hb + (size_t)(dir * BB + rowA0) * 512 + ksub * 4;
    const unsigned int* h1p = hb + (size_t)(dir * BB + rowA1) * 512 + ksub * 4;
#pragma unroll
    for (int ksl = 0; ksl < 32; ++ksl) {
      uint4 u0 = *(const uint4*)(h0p + ksl * 16);
      uint4 u1 = *(const uint4*)(h1p + ksl * 16);
      bf16x8 b0 = *(const bf16x8*)(smem + (ksl * 2 + 0) * 1024 + (lane << 4));
      bf16x8 b1 = *(const bf16x8*)(smem + (ksl * 2 + 1) * 1024 + (lane << 4));
      a00 = __builtin_amdgcn_mfma_f32_16x16x32_bf16(bc8(u0), b0, a00, 0, 0, 0);
      a01 = __builtin_amdgcn_mfma_f32_16x16x32_bf16(bc8(u0), b1, a01, 0, 0, 0);
      a10 = __builtin_amdgcn_mfma_f32_16x16x32_bf16(bc8(u1), b0, a10, 0, 0, 0);
      a11 = __builtin_amdgcn_mfma_f32_16x16x32_bf16(bc8(u1), b1, a11, 0, 0, 0);
    }
  };

  // prologue: x-part for step 0
  x_phase(dir ? TT - 1 : 0);
  unsigned int pcount = 0;

  for (int s = 0; s < TT; ++s) {
    const int t = dir ? (TT - 1 - s) : s;

    // ---- wait for h(s): own-dir 64 slots >= s; then ACQUIRE (L2 inv)
    if (tid < 64) {
      const int si = dir * 64 + lane;
      while (true) {
        unsigned v = __hip_atomic_load(&stepslot[si], __ATOMIC_RELAXED, AGENT);
        if (__all((int)(v >= (unsigned)s))) break;
        __builtin_amdgcn_s_sleep(1);
      }
      (void)__hip_atomic_load(&stepslot[si], __ATOMIC_ACQUIRE, AGENT);
    }
    __syncthreads();

    h_phase(s & 1);

    // ---- gate exchange through LDS (padded [128][33] f32)
    float* exch = (float*)(smem + 65536);
    {
      const int rb4 = (lane >> 4) * 4;
#pragma unroll
      for (int m = 0; m < 2; ++m)
#pragma unroll
        for (int r = 0; r < 4; ++r) {
          int lr = wm * 32 + m * 16 + rb4 + r;
          exch[lr * 33 + (lane & 15)]      = (m ? a10 : a00)[r];
          exch[lr * 33 + 16 + (lane & 15)] = (m ? a11 : a01)[r];
        }
    }
    __syncthreads();

    unsigned int* hw = hpk + (size_t)((s & 1) ^ 1) * PARW;
#pragma unroll
    for (int q = 0; q < 4; ++q) {
      int p = q * 256 + tid;
      int u = p >> 7;        // 0..7
      int lr = p & 127;      // batch row
      float gi = exch[lr * 33 + u];
      float gf = exch[lr * 33 + 8 + u];
      float gg = exch[lr * 33 + 16 + u];
      float go = exch[lr * 33 + 24 + u];
      float si = sigm(gi), sf = sigm(gf), tg = tanh_f(gg), so = sigm(go);
      float c = sf * cst[q] + si * tg;
      cst[q] = c;
      float h = so * tanh_f(c);
      ushort hi = f2bf(h);
      ushort lo = f2bf(h - bf2f(hi));
      int jq = nb * 8 + u;
      __hip_atomic_store(hw + (size_t)(dir * BB + lr) * 512 + jq,
                         (unsigned int)hi | ((unsigned int)lo << 16),
                         __ATOMIC_RELAXED, AGENT);
      if constexpr (IS_L0)
        __hip_atomic_store(hseq + ((size_t)t * BB + lr) * 1024 + dir * HH + jq,
                           hi, __ATOMIC_RELAXED, AGENT);
      else
        __hip_atomic_store(ring + ((size_t)(dir * 64 + (t & 63)) * BB + lr) * HH + jq,
                           hi, __ATOMIC_RELAXED, AGENT);
    }

    __syncthreads();  // drain sc1 stores (vmcnt 0) + protect exch
    if (tid == 0)
      __hip_atomic_store(&stepslot[wg], (unsigned)(s + 1), __ATOMIC_RELAXED, AGENT);

    // x-part for step s+1 in the barrier-wait shadow
    if (s + 1 < TT) x_phase(dir ? (TT - 2 - s) : (s + 1));

    if constexpr (!IS_L0) {
      if ((s & 63) == 63) {
        // all 128 WGs' ring writes for this chunk done; ACQUIRE for plain reads
        if (tid < 64) {
          const unsigned tgt = (unsigned)(s + 1);
          while (true) {
            unsigned v0 = __hip_atomic_load(&stepslot[lane], __ATOMIC_RELAXED, AGENT);
            unsigned v1 = __hip_atomic_load(&stepslot[64 + lane], __ATOMIC_RELAXED, AGENT);
            if (__all((int)(v0 >= tgt && v1 >= tgt))) break;
            __builtin_amdgcn_s_sleep(1);
          }
          (void)__hip_atomic_load(&stepslot[lane], __ATOMIC_ACQUIRE, AGENT);
        }
        __syncthreads();
        proj_body(s >> 6, wg, tid, ring, WoB, bout, out, smem + 65536);
        __syncthreads();  // proj loads drained
        ++pcount;
        if (tid == 0)
          __hip_atomic_store(&projslot[wg], pcount, __ATOMIC_RELAXED, AGENT);
        if (tid < 64) {
          while (true) {
            unsigned v0 = __hip_atomic_load(&projslot[lane], __ATOMIC_RELAXED, AGENT);
            unsigned v1 = __hip_atomic_load(&projslot[64 + lane], __ATOMIC_RELAXED, AGENT);
            if (__all((int)(v0 >= pcount && v1 >= pcount))) break;
            __builtin_amdgcn_s_sleep(1);
          }
        }
        __syncthreads();
      }
    }
  }
}

// ---------------------------------------------------------------------------
extern "C" void kernel_launch(void* const* d_in, const int* in_sizes, int n_in,
                              void* d_out, int out_size, void* d_ws, size_t ws_size,
                              hipStream_t stream) {
  const int* sent = (const int*)d_in[0];
  const float* emb = (const float*)d_in[1];
  const float* Wih0 = (const float*)d_in[2];
  const float* Whh0 = (const float*)d_in[3];
  const float* bih0 = (const float*)d_in[4];
  const float* bhh0 = (const float*)d_in[5];
  const float* Wih1 = (const float*)d_in[6];
  const float* Whh1 = (const float*)d_in[7];
  const float* bih1 = (const float*)d_in[8];
  const float* bhh1 = (const float*)d_in[9];
  const float* Wout = (const float*)d_in[10];
  const float* bout = (const float*)d_in[11];
  float* out = (float*)d_out;

  const size_t NEED = 179635200;
  if (ws_size < NEED) {
    report_ws<<<(out_size + 255) / 256, 256, 0, stream>>>(out, out_size,
                                                          (float)(ws_size >> 20));
    return;
  }
  char* ws = (char*)d_ws;
  ushort* h0   = (ushort*)(ws + 0);                 // 134,217,728  [T][B][1024]
  ushort* Wp0  = (ushort*)(ws + 134217728);         //  10,485,760  frag-packed KSL=40
  ushort* Wp1  = (ushort*)(ws + 144703488);         //  16,777,216  frag-packed KSL=64
  ushort* WoB  = (ushort*)(ws + 161480704);         //     262,144
  ushort* embB = (ushort*)(ws + 161742848);         //      65,536
  unsigned int* hpk = (unsigned int*)(ws + 161808384); // 1,048,576 [2][2][B][512] u32
  ushort* ring = (ushort*)(ws + 162856960);         //  16,777,216  [2][64][B][512]
  unsigned int* bars = (unsigned int*)(ws + 179634176);  // 1024B (256 u32)

  pack_emb<<<128, 256, 0, stream>>>(emb, embB);
  pack_w<<<20480, 256, 0, stream>>>(Whh0, Wih0, Wp0, 40, 256);
  pack_w<<<32768, 256, 0, stream>>>(Whh1, Wih1, Wp1, 64, 1024);
  pack_wout<<<512, 256, 0, stream>>>(Wout, WoB);

  // layer 0 (persistent)
  zero_h<<<128, 256, 0, stream>>>(hpk, bars);
  lstm_persist<1, 8><<<128, 256, 0, stream>>>(
      Wp0, h0, sent, embB, hpk, ring, WoB, bout, out, bih0, bhh0, bars);

  // layer 1 (persistent, proj folded in)
  zero_h<<<128, 256, 0, stream>>>(hpk, bars);
  lstm_persist<0, 32><<<128, 256, 0, stream>>>(
      Wp1, h0, sent, embB, hpk, ring, WoB, bout, out, bih1, bhh1, bars);
}

// Round 8
// 20034.543 us; speedup vs baseline: 1.6484x; 1.1519x over previous
//
#include <hip/hip_runtime.h>
#include <stdint.h>

// ---------------------------------------------------------------------------
// 2-layer BiLSTM LM: emb -> BiLSTM(E=256->H=512) -> BiLSTM(1024->512) -> proj
// V=128 E=256 H=512 B=128 T=512.
//
// Round 8 (r7 post-mortem: WRITE 4.26GB/dispatch = 16x amplification from
// scattered 4B sc1 stores; FETCH 2.19GB = per-step ACQUIRE-inv evicting
// streamed x-weights. Fix both, keep the r7 skeleton):
//  - hpk re-layout [par][dir][nb][b][8u]: WG output = 4KB contiguous chunk;
//    epilogue = 2 threads/row x 4 units, 16B contiguous u64 sc1 stores.
//  - h reads = relaxed sc1 u64 atomic loads (LLC-served, r6-validated) =>
//    per-step ACQUIRE deleted entirely; x-W and hseq stay L2-resident.
//  - hseq (L0 out) = plain cached stores (consumed by next kernel launch).
//  - ring writes = 8B packed sc1 stores; proj keeps its 8x/dispatch
//    ACQUIRE-inv + slot barriers (r7-proven).
//  - Whh frag-packed resident in LDS (64KB); x_phase in barrier shadow;
//    slot-array barrier; c-state in registers.
//
// Numerics (validated r1..r7, absmax 1.95e-3): bf16 MFMA fp32-accum; c f32;
// h carried hi/lo bf16 packed in u32; W k-interleaved dup (k>>1).
// ---------------------------------------------------------------------------

#define TT 512
#define BB 128
#define HH 512
#define VV 128
#define AGENT __HIP_MEMORY_SCOPE_AGENT

typedef __attribute__((ext_vector_type(8))) short bf16x8;
typedef __attribute__((ext_vector_type(4))) float f32x4;

__device__ __forceinline__ ushort f2bf(float f) {
  uint32_t u = __builtin_bit_cast(uint32_t, f);
  u += 0x7FFFu + ((u >> 16) & 1u);
  return (ushort)(u >> 16);
}
__device__ __forceinline__ float bf2f(ushort h) {
  uint32_t u = ((uint32_t)h) << 16;
  return __builtin_bit_cast(float, u);
}
__device__ __forceinline__ float sigm(float x) { return 1.f / (1.f + __expf(-x)); }
__device__ __forceinline__ float tanh_f(float x) { return 1.f - 2.f / (__expf(2.f * x) + 1.f); }

__global__ __launch_bounds__(256) void report_ws(float* __restrict__ out, int n, float val) {
  int i = blockIdx.x * 256 + threadIdx.x;
  if (i < n) out[i] = val;
}

__global__ __launch_bounds__(256) void pack_emb(const float* __restrict__ emb,
                                                ushort* __restrict__ embB) {
  int i = blockIdx.x * 256 + threadIdx.x;  // 32768
  embB[i] = f2bf(emb[i]);
}

// Frag-packed W (unchanged from r7).
// Slice (d, nb) = 2*KSL frags of 1KB. frag f = kslg*2 + n2:
//   elem (l, e): rloc = n2*16 + (l&15); grow = (rloc>>3)*512 + nb*8 + (rloc&7)
//   k = kslg*32 + (l>>4)*8 + e; k<1024 -> Whh[d][grow][k>>1]; else Wih[k-1024].
__global__ __launch_bounds__(256) void pack_w(const float* __restrict__ Whh,
                                              const float* __restrict__ Wih,
                                              ushort* __restrict__ Wp,
                                              int KSL, int Ein) {
  size_t idx = (size_t)blockIdx.x * 256 + threadIdx.x;
  size_t total = (size_t)128 * 2 * KSL * 512;
  if (idx >= total) return;
  int e = (int)(idx & 7);
  int l = (int)((idx >> 3) & 63);
  int f = (int)((idx >> 9) % (size_t)(2 * KSL));
  int sl = (int)(idx / ((size_t)1024 * KSL));
  int nb = sl & 63, d = sl >> 6;
  int n2 = f & 1, kslg = f >> 1;
  int rloc = n2 * 16 + (l & 15);
  int grow = (rloc >> 3) * 512 + nb * 8 + (rloc & 7);
  int k = kslg * 32 + (l >> 4) * 8 + e;
  float val;
  if (k < 1024) val = Whh[((size_t)d * 2048 + grow) * 512 + (k >> 1)];
  else          val = Wih[((size_t)d * 2048 + grow) * Ein + (k - 1024)];
  Wp[idx] = f2bf(val);
}

__global__ __launch_bounds__(256) void pack_wout(const float* __restrict__ Wo,
                                                 ushort* __restrict__ WoB) {
  int i = blockIdx.x * 256 + threadIdx.x;  // 131072
  WoB[i] = f2bf(Wo[i]);
}

// zero parity-0 h buffer (512KB) + slot arrays (256 u32)
__global__ __launch_bounds__(256) void zero_h(unsigned int* __restrict__ hpk,
                                              unsigned int* __restrict__ bars) {
  int i = blockIdx.x * 256 + threadIdx.x;
  ((uint4*)hpk)[i] = make_uint4(0, 0, 0, 0);
  if (i < 256) bars[i] = 0;
}

// ---------------------------------------------------------------------------
// Projection chunk (layer-1, all 128 WGs). BK=32, 16KB LDS. (r7-validated.)
// ---------------------------------------------------------------------------
__device__ void proj_body(int k, int wg, int tid, const ushort* __restrict__ ring,
                          const ushort* __restrict__ WoB, const float* __restrict__ bout,
                          float* __restrict__ out, char* shm) {
  const int slot = wg & 63;
  const int dirp = wg >> 6;
  const int tp = (dirp ? (448 - 64 * k) : (64 * k)) + slot;
  const int mode = (k >= 4);
  ushort* As = (ushort*)shm;            // [128][32] swizzled 64B rows
  ushort* Bs = (ushort*)(shm + 8192);
  const int wm = tid >> 6;
  const int lane = tid & 63;

  f32x4 acc[2][8] = {};

  for (int kt = 0; kt < 16; ++kt) {     // K = 512
    uint4 ra[2], rb[2];
#pragma unroll
    for (int it = 0; it < 2; ++it) {
      int c = it * 256 + tid;
      int r = c >> 2, bq = c & 3;
      ra[it] = *(const uint4*)(ring + ((size_t)(dirp * 64 + slot) * BB + r) * HH + kt * 32 + bq * 8);
      rb[it] = *(const uint4*)(WoB + (size_t)r * 1024 + dirp * HH + kt * 32 + bq * 8);
    }
    __syncthreads();
#pragma unroll
    for (int it = 0; it < 2; ++it) {
      int c = it * 256 + tid;
      int r = c >> 2, bq = c & 3;
      int off = r * 64 + ((bq << 4) ^ ((r & 3) << 4));
      *(uint4*)((char*)As + off) = ra[it];
      *(uint4*)((char*)Bs + off) = rb[it];
    }
    __syncthreads();
    const int kb = (lane >> 4) << 4;
    bf16x8 a[2], bb[8];
#pragma unroll
    for (int m = 0; m < 2; ++m) {
      int row = wm * 32 + m * 16 + (lane & 15);
      a[m] = *(const bf16x8*)((const char*)As + row * 64 + (kb ^ ((row & 3) << 4)));
    }
#pragma unroll
    for (int n = 0; n < 8; ++n) {
      int row = n * 16 + (lane & 15);
      bb[n] = *(const bf16x8*)((const char*)Bs + row * 64 + (kb ^ ((row & 3) << 4)));
    }
#pragma unroll
    for (int m = 0; m < 2; ++m)
#pragma unroll
      for (int n = 0; n < 8; ++n)
        acc[m][n] = __builtin_amdgcn_mfma_f32_16x16x32_bf16(a[m], bb[n], acc[m][n], 0, 0, 0);
  }

  const int rbase = (lane >> 4) * 4;
#pragma unroll
  for (int n = 0; n < 8; ++n) {
    int v = n * 16 + (lane & 15);
    float bo = bout[v];
#pragma unroll
    for (int m = 0; m < 2; ++m)
#pragma unroll
      for (int r = 0; r < 4; ++r) {
        int b = wm * 32 + m * 16 + rbase + r;
        size_t o = ((size_t)b * TT + tp) * VV + v;
        if (mode) (void)unsafeAtomicAdd(&out[o], acc[m][n][r]);
        else      __hip_atomic_store(&out[o], acc[m][n][r] + bo, __ATOMIC_RELAXED, AGENT);
      }
  }
}

// ---------------------------------------------------------------------------
// Persistent LSTM layer. 128 WGs = (dir 2)(nb 64), 256 threads (4 waves).
// Whh resident in LDS; h via LLC (sc1 u64 atomics, contiguous chunks);
// x-part streamed through L2 (never invalidated in the step loop).
// ---------------------------------------------------------------------------
template <int IS_L0, int KSLX>
__global__ __launch_bounds__(256, 1) void lstm_persist(
    const ushort* __restrict__ Wp,    // [128 slices][2*KSL frags][512]
    ushort* __restrict__ hseq,        // [T][B][1024]: L0 writes (plain), L1 reads x
    const int* __restrict__ sent,     // L0: [B][T]
    const ushort* __restrict__ embB,  // L0: [128][256]
    unsigned int* __restrict__ hpk,   // [2 par][2 dir][64 nb][128 b][8 u] u32
    ushort* __restrict__ ring,        // L1: [2][64][B][512]
    const ushort* __restrict__ WoB,   // L1: [V][1024]
    const float* __restrict__ bout,   // L1: [V]
    float* __restrict__ out,          // L1: [B][T][V]
    const float* __restrict__ bih, const float* __restrict__ bhh,
    unsigned int* __restrict__ bars) {
  constexpr int KSL = 32 + KSLX;
  const int wg = blockIdx.x;
  const int nb = wg & 63;
  const int dir = wg >> 6;
  const int tid = threadIdx.x;
  const int wm = tid >> 6;
  const int lane = tid & 63;
  const int PARW = 2 * BB * 512;      // u32 per parity buffer

  __shared__ __align__(16) char smem[65536 + 16896];  // 64KB Whh-frags + exch

  const ushort* wslice = Wp + (size_t)(dir * 64 + nb) * (2 * KSL * 512);

  // ---- preload Whh-part W (first 64KB of slice) into LDS, once
  for (int i = tid; i < 4096; i += 256)
    ((uint4*)smem)[i] = ((const uint4*)wslice)[i];
  __syncthreads();

  const int rowA0 = wm * 32 + (lane & 15);   // A-fragment rows (fixed)
  const int rowA1 = rowA0 + 16;
  const int ksub = lane >> 4;

  const int ju = nb * 8 + (lane & 7);
  const float biJ = bih[dir * 2048 + ju] + bhh[dir * 2048 + ju];
  const float bfJ = bih[dir * 2048 + 512 + ju] + bhh[dir * 2048 + 512 + ju];
  const float bgJ = bih[dir * 2048 + 1024 + ju] + bhh[dir * 2048 + 1024 + ju];
  const float boJ = bih[dir * 2048 + 1536 + ju] + bhh[dir * 2048 + 1536 + ju];
  const float bias0 = (lane & 8) ? bfJ : biJ;
  const float bias1 = (lane & 8) ? boJ : bgJ;

  float cst[4] = {0.f, 0.f, 0.f, 0.f};  // c for this thread's (row, 4 units)

  unsigned int* stepslot = bars;         // [128]
  unsigned int* projslot = bars + 128;   // [128]

  f32x4 a00, a01, a10, a11;

  auto bc8 = [](uint4 u) { return __builtin_bit_cast(bf16x8, u); };

  const ushort* wx = wslice + 32768;     // x-frag base (ushort units)

  auto x_phase = [&](int t) {
    a00 = (f32x4){bias0, bias0, bias0, bias0};
    a01 = (f32x4){bias1, bias1, bias1, bias1};
    a10 = a00; a11 = a01;
    const ushort *xr0, *xr1;
    if constexpr (IS_L0) {
      xr0 = embB + sent[rowA0 * TT + t] * 256 + ksub * 8;
      xr1 = embB + sent[rowA1 * TT + t] * 256 + ksub * 8;
    } else {
      xr0 = hseq + ((size_t)t * BB + rowA0) * 1024 + ksub * 8;
      xr1 = hseq + ((size_t)t * BB + rowA1) * 1024 + ksub * 8;
    }
    const ushort* wxl = wx + lane * 8;
#pragma unroll
    for (int ksl = 0; ksl < KSLX; ++ksl) {
      uint4 u0 = *(const uint4*)(xr0 + ksl * 32);
      uint4 u1 = *(const uint4*)(xr1 + ksl * 32);
      bf16x8 b0 = *(const bf16x8*)(wxl + (ksl * 2 + 0) * 512);
      bf16x8 b1 = *(const bf16x8*)(wxl + (ksl * 2 + 1) * 512);
      a00 = __builtin_amdgcn_mfma_f32_16x16x32_bf16(bc8(u0), b0, a00, 0, 0, 0);
      a01 = __builtin_amdgcn_mfma_f32_16x16x32_bf16(bc8(u0), b1, a01, 0, 0, 0);
      a10 = __builtin_amdgcn_mfma_f32_16x16x32_bf16(bc8(u1), b0, a10, 0, 0, 0);
      a11 = __builtin_amdgcn_mfma_f32_16x16x32_bf16(bc8(u1), b1, a11, 0, 0, 0);
    }
  };

  // h-part: acc += h(par) @ Whh^T; h via sc1 u64 atomic loads (LLC-served).
  auto h_phase = [&](int par) {
    const unsigned long long* hb =
        (const unsigned long long*)(hpk + (size_t)par * PARW);
#pragma unroll
    for (int ksl = 0; ksl < 32; ++ksl) {
      const int jj = ksl * 16 + ksub * 4;   // packed-u32 unit index base
      const int nbr = jj >> 3;
      const int uq = (jj & 7) >> 1;         // u64 offset in row chunk (0 or 2)
      const unsigned long long* p0 =
          hb + (((size_t)(dir * 64 + nbr) * 128 + rowA0) * 4 + uq);
      const unsigned long long* p1 =
          hb + (((size_t)(dir * 64 + nbr) * 128 + rowA1) * 4 + uq);
      unsigned long long x0 = __hip_atomic_load(p0 + 0, __ATOMIC_RELAXED, AGENT);
      unsigned long long x1 = __hip_atomic_load(p0 + 1, __ATOMIC_RELAXED, AGENT);
      unsigned long long y0 = __hip_atomic_load(p1 + 0, __ATOMIC_RELAXED, AGENT);
      unsigned long long y1 = __hip_atomic_load(p1 + 1, __ATOMIC_RELAXED, AGENT);
      uint4 u0 = make_uint4((uint32_t)x0, (uint32_t)(x0 >> 32),
                            (uint32_t)x1, (uint32_t)(x1 >> 32));
      uint4 u1 = make_uint4((uint32_t)y0, (uint32_t)(y0 >> 32),
                            (uint32_t)y1, (uint32_t)(y1 >> 32));
      bf16x8 b0 = *(const bf16x8*)(smem + (ksl * 2 + 0) * 1024 + (lane << 4));
      bf16x8 b1 = *(const bf16x8*)(smem + (ksl * 2 + 1) * 1024 + (lane << 4));
      a00 = __builtin_amdgcn_mfma_f32_16x16x32_bf16(bc8(u0), b0, a00, 0, 0, 0);
      a01 = __builtin_amdgcn_mfma_f32_16x16x32_bf16(bc8(u0), b1, a01, 0, 0, 0);
      a10 = __builtin_amdgcn_mfma_f32_16x16x32_bf16(bc8(u1), b0, a10, 0, 0, 0);
      a11 = __builtin_amdgcn_mfma_f32_16x16x32_bf16(bc8(u1), b1, a11, 0, 0, 0);
    }
  };

  // prologue: x-part for step 0
  x_phase(dir ? TT - 1 : 0);
  unsigned int pcount = 0;

  for (int s = 0; s < TT; ++s) {
    const int t = dir ? (TT - 1 - s) : s;

    // ---- wait for h(s): own-dir 64 slots >= s (no cache maintenance)
    if (tid < 64) {
      const int si = dir * 64 + lane;
      while (true) {
        unsigned v = __hip_atomic_load(&stepslot[si], __ATOMIC_RELAXED, AGENT);
        if (__all((int)(v >= (unsigned)s))) break;
        __builtin_amdgcn_s_sleep(1);
      }
    }
    __syncthreads();

    h_phase(s & 1);

    // ---- gate exchange through LDS (padded [128][33] f32)
    float* exch = (float*)(smem + 65536);
    {
      const int rb4 = (lane >> 4) * 4;
#pragma unroll
      for (int m = 0; m < 2; ++m)
#pragma unroll
        for (int r = 0; r < 4; ++r) {
          int lr = wm * 32 + m * 16 + rb4 + r;
          exch[lr * 33 + (lane & 15)]      = (m ? a10 : a00)[r];
          exch[lr * 33 + 16 + (lane & 15)] = (m ? a11 : a01)[r];
        }
    }
    __syncthreads();

    // ---- epilogue: 2 threads/row x 4 units; 16B contiguous sc1 stores
    unsigned int* hw = hpk + (size_t)((s & 1) ^ 1) * PARW;
    {
      const int lr = tid >> 1;
      const int uh = (tid & 1) * 4;
      ushort hh[4], hl[4];
#pragma unroll
      for (int i = 0; i < 4; ++i) {
        const int u = uh + i;
        float gi = exch[lr * 33 + u];
        float gf = exch[lr * 33 + 8 + u];
        float gg = exch[lr * 33 + 16 + u];
        float go = exch[lr * 33 + 24 + u];
        float si = sigm(gi), sf = sigm(gf), tg = tanh_f(gg), so = sigm(go);
        float c = sf * cst[i] + si * tg;
        cst[i] = c;
        float h = so * tanh_f(c);
        hh[i] = f2bf(h);
        hl[i] = f2bf(h - bf2f(hh[i]));
      }
      unsigned long long p0 =
          (unsigned long long)((uint32_t)hh[0] | ((uint32_t)hl[0] << 16)) |
          ((unsigned long long)((uint32_t)hh[1] | ((uint32_t)hl[1] << 16)) << 32);
      unsigned long long p1 =
          (unsigned long long)((uint32_t)hh[2] | ((uint32_t)hl[2] << 16)) |
          ((unsigned long long)((uint32_t)hh[3] | ((uint32_t)hl[3] << 16)) << 32);
      unsigned long long* dst =
          (unsigned long long*)(hw + (((size_t)(dir * 64 + nb) * 128 + lr) * 8 + uh));
      __hip_atomic_store(dst + 0, p0, __ATOMIC_RELAXED, AGENT);
      __hip_atomic_store(dst + 1, p1, __ATOMIC_RELAXED, AGENT);
      unsigned long long hpack =
          (unsigned long long)hh[0] | ((unsigned long long)hh[1] << 16) |
          ((unsigned long long)hh[2] << 32) | ((unsigned long long)hh[3] << 48);
      if constexpr (IS_L0) {
        *(unsigned long long*)(hseq + ((size_t)t * BB + lr) * 1024 + dir * HH +
                               nb * 8 + uh) = hpack;   // plain: next-kernel consumer
      } else {
        __hip_atomic_store(
            (unsigned long long*)(ring + ((size_t)(dir * 64 + (t & 63)) * BB + lr) * HH +
                                  nb * 8 + uh),
            hpack, __ATOMIC_RELAXED, AGENT);
      }
    }

    __syncthreads();  // drain stores (vmcnt 0) + protect exch
    if (tid == 0)
      __hip_atomic_store(&stepslot[wg], (unsigned)(s + 1), __ATOMIC_RELAXED, AGENT);

    // x-part for step s+1 in the barrier-wait shadow
    if (s + 1 < TT) x_phase(dir ? (TT - 2 - s) : (s + 1));

    if constexpr (!IS_L0) {
      if ((s & 63) == 63) {
        // all 128 WGs' ring writes done; ACQUIRE (L2 inv) for plain ring reads
        if (tid < 64) {
          const unsigned tgt = (unsigned)(s + 1);
          while (true) {
            unsigned v0 = __hip_atomic_load(&stepslot[lane], __ATOMIC_RELAXED, AGENT);
            unsigned v1 = __hip_atomic_load(&stepslot[64 + lane], __ATOMIC_RELAXED, AGENT);
            if (__all((int)(v0 >= tgt && v1 >= tgt))) break;
            __builtin_amdgcn_s_sleep(1);
          }
          (void)__hip_atomic_load(&stepslot[lane], __ATOMIC_ACQUIRE, AGENT);
        }
        __syncthreads();
        proj_body(s >> 6, wg, tid, ring, WoB, bout, out, smem + 65536);
        __syncthreads();  // proj loads drained
        ++pcount;
        if (tid == 0)
          __hip_atomic_store(&projslot[wg], pcount, __ATOMIC_RELAXED, AGENT);
        if (tid < 64) {
          while (true) {
            unsigned v0 = __hip_atomic_load(&projslot[lane], __ATOMIC_RELAXED, AGENT);
            unsigned v1 = __hip_atomic_load(&projslot[64 + lane], __ATOMIC_RELAXED, AGENT);
            if (__all((int)(v0 >= pcount && v1 >= pcount))) break;
            __builtin_amdgcn_s_sleep(1);
          }
        }
        __syncthreads();
      }
    }
  }
}

// ---------------------------------------------------------------------------
extern "C" void kernel_launch(void* const* d_in, const int* in_sizes, int n_in,
                              void* d_out, int out_size, void* d_ws, size_t ws_size,
                              hipStream_t stream) {
  const int* sent = (const int*)d_in[0];
  const float* emb = (const float*)d_in[1];
  const float* Wih0 = (const float*)d_in[2];
  const float* Whh0 = (const float*)d_in[3];
  const float* bih0 = (const float*)d_in[4];
  const float* bhh0 = (const float*)d_in[5];
  const float* Wih1 = (const float*)d_in[6];
  const float* Whh1 = (const float*)d_in[7];
  const float* bih1 = (const float*)d_in[8];
  const float* bhh1 = (const float*)d_in[9];
  const float* Wout = (const float*)d_in[10];
  const float* bout = (const float*)d_in[11];
  float* out = (float*)d_out;

  const size_t NEED = 179635200;
  if (ws_size < NEED) {
    report_ws<<<(out_size + 255) / 256, 256, 0, stream>>>(out, out_size,
                                                          (float)(ws_size >> 20));
    return;
  }
  char* ws = (char*)d_ws;
  ushort* h0   = (ushort*)(ws + 0);                 // 134,217,728  [T][B][1024]
  ushort* Wp0  = (ushort*)(ws + 134217728);         //  10,485,760  frag-packed KSL=40
  ushort* Wp1  = (ushort*)(ws + 144703488);         //  16,777,216  frag-packed KSL=64
  ushort* WoB  = (ushort*)(ws + 161480704);         //     262,144
  ushort* embB = (ushort*)(ws + 161742848);         //      65,536
  unsigned int* hpk = (unsigned int*)(ws + 161808384); // 1,048,576 [2][2][64][128][8] u32
  ushort* ring = (ushort*)(ws + 162856960);         //  16,777,216  [2][64][B][512]
  unsigned int* bars = (unsigned int*)(ws + 179634176);  // 1024B (256 u32)

  pack_emb<<<128, 256, 0, stream>>>(emb, embB);
  pack_w<<<20480, 256, 0, stream>>>(Whh0, Wih0, Wp0, 40, 256);
  pack_w<<<32768, 256, 0, stream>>>(Whh1, Wih1, Wp1, 64, 1024);
  pack_wout<<<512, 256, 0, stream>>>(Wout, WoB);

  // layer 0 (persistent)
  zero_h<<<128, 256, 0, stream>>>(hpk, bars);
  lstm_persist<1, 8><<<128, 256, 0, stream>>>(
      Wp0, h0, sent, embB, hpk, ring, WoB, bout, out, bih0, bhh0, bars);

  // layer 1 (persistent, proj folded in)
  zero_h<<<128, 256, 0, stream>>>(hpk, bars);
  lstm_persist<0, 32><<<128, 256, 0, stream>>>(
      Wp1, h0, sent, embB, hpk, ring, WoB, bout, out, bih1, bhh1, bars);
}

// Round 9
// 11892.429 us; speedup vs baseline: 2.7769x; 1.6846x over previous
//
#include <hip/hip_runtime.h>
#include <stdint.h>

// ---------------------------------------------------------------------------
// 2-layer BiLSTM LM: emb -> BiLSTM(E=256->H=512) -> BiLSTM(1024->512) -> proj
// V=128 E=256 H=512 B=128 T=512.
//
// Round 9 (r8 post-mortem: step time = iteration-serialized L2/LLC latency,
// half the chip idle, x-weights still streaming):
//  - ALL weights LDS-resident: h stored as separate hi/lo PLANES (not W dup)
//    -> W slice halves to 96KB (L1) and fits LDS; zero W global traffic in
//    the step loop. MFMA does hi and lo passes against the same W frags.
//  - 256 WGs = (dir 2)(nb 64)(mh 2), M=64/WG: all 256 CUs busy, per-lane
//    load chain halved.
//  - batch-then-consume: all h loads (64 u64 sc1) and x loads (XS uint4)
//    issued into fully-unrolled register arrays BEFORE consumption -> one
//    exposed latency per phase instead of one per iteration.
//  - skeleton (sc1 h exchange, slot barriers, proj chunks w/ 8x ACQUIRE,
//    write/add pairing) unchanged from r8 (validated).
//
// Numerics (validated r1..r8, absmax 1.95e-3): bf16 MFMA fp32-accum; c f32;
// h carried as hi/lo bf16 planes; gates = Whh*(hi+lo) + Wih*x + b.
// ---------------------------------------------------------------------------

#define TT 512
#define BB 128
#define HH 512
#define VV 128
#define AGENT __HIP_MEMORY_SCOPE_AGENT

typedef __attribute__((ext_vector_type(8))) short bf16x8;
typedef __attribute__((ext_vector_type(4))) float f32x4;

__device__ __forceinline__ ushort f2bf(float f) {
  uint32_t u = __builtin_bit_cast(uint32_t, f);
  u += 0x7FFFu + ((u >> 16) & 1u);
  return (ushort)(u >> 16);
}
__device__ __forceinline__ float bf2f(ushort h) {
  uint32_t u = ((uint32_t)h) << 16;
  return __builtin_bit_cast(float, u);
}
__device__ __forceinline__ float sigm(float x) { return 1.f / (1.f + __expf(-x)); }
__device__ __forceinline__ float tanh_f(float x) { return 1.f - 2.f / (__expf(2.f * x) + 1.f); }
__device__ __forceinline__ bf16x8 bc8(uint4 u) { return __builtin_bit_cast(bf16x8, u); }

__global__ __launch_bounds__(256) void report_ws(float* __restrict__ out, int n, float val) {
  int i = blockIdx.x * 256 + threadIdx.x;
  if (i < n) out[i] = val;
}

__global__ __launch_bounds__(256) void pack_emb(const float* __restrict__ emb,
                                                ushort* __restrict__ embB) {
  int i = blockIdx.x * 256 + threadIdx.x;  // 32768
  embB[i] = f2bf(emb[i]);
}

// Frag-packed W, NO dup. Slice (d, nb) = 2*KSL frags of 1KB.
// frag f = kslg*2 + n2; elem (l,e): rloc = n2*16 + (l&15);
// grow = (rloc>>3)*512 + nb*8 + (rloc&7); k = kslg*32 + (l>>4)*8 + e.
// k<512 -> Whh[d][grow][k]; else Wih[d][grow][k-512].
__global__ __launch_bounds__(256) void pack_w(const float* __restrict__ Whh,
                                              const float* __restrict__ Wih,
                                              ushort* __restrict__ Wp,
                                              int KSL, int Ein) {
  size_t idx = (size_t)blockIdx.x * 256 + threadIdx.x;
  size_t total = (size_t)128 * 2 * KSL * 512;
  if (idx >= total) return;
  int e = (int)(idx & 7);
  int l = (int)((idx >> 3) & 63);
  int f = (int)((idx >> 9) % (size_t)(2 * KSL));
  int sl = (int)(idx / ((size_t)1024 * KSL));
  int nb = sl & 63, d = sl >> 6;
  int n2 = f & 1, kslg = f >> 1;
  int rloc = n2 * 16 + (l & 15);
  int grow = (rloc >> 3) * 512 + nb * 8 + (rloc & 7);
  int k = kslg * 32 + (l >> 4) * 8 + e;
  float val;
  if (k < 512) val = Whh[((size_t)d * 2048 + grow) * 512 + k];
  else         val = Wih[((size_t)d * 2048 + grow) * Ein + (k - 512)];
  Wp[idx] = f2bf(val);
}

__global__ __launch_bounds__(256) void pack_wout(const float* __restrict__ Wo,
                                                 ushort* __restrict__ WoB) {
  int i = blockIdx.x * 256 + threadIdx.x;  // 131072
  WoB[i] = f2bf(Wo[i]);
}

// zero hpk (1MB = 65536 uint4) + barrier slots (512 u32)
__global__ __launch_bounds__(256) void zero_h(unsigned int* __restrict__ hpk,
                                              unsigned int* __restrict__ bars) {
  int i = blockIdx.x * 256 + threadIdx.x;  // grid 256
  ((uint4*)hpk)[i] = make_uint4(0, 0, 0, 0);
  if (i < 512) bars[i] = 0;
}

// ---------------------------------------------------------------------------
// Projection chunk: WG handles t = base(dirp,k)+slot, rows bh*64..+63,
// all 128 v, K = 512 (one dir's half). k<=3: write (+bout); k>=4: atomic add.
// ---------------------------------------------------------------------------
__device__ void proj_body(int k, int slot, int dirp, int bh, int tid,
                          const ushort* __restrict__ ring,
                          const ushort* __restrict__ WoB,
                          const float* __restrict__ bout,
                          float* __restrict__ out, char* shm) {
  const int tp = (dirp ? (448 - 64 * k) : (64 * k)) + slot;
  const int mode = (k >= 4);
  ushort* As = (ushort*)shm;            // [64][32] swizzled 64B rows
  ushort* Bs = (ushort*)(shm + 4096);   // [128][32] swizzled
  const int wm = tid >> 6;
  const int lane = tid & 63;

  f32x4 acc[8] = {};

  for (int kt = 0; kt < 16; ++kt) {     // K = 512
    const int rA = tid >> 2, qA = tid & 3;
    uint4 ra = *(const uint4*)(ring + ((size_t)(dirp * 64 + slot) * BB + bh * 64 + rA) * HH +
                               kt * 32 + qA * 8);
    uint4 rb[2];
#pragma unroll
    for (int it = 0; it < 2; ++it) {
      int c = it * 256 + tid;
      int rB = c >> 2, qB = c & 3;
      rb[it] = *(const uint4*)(WoB + (size_t)rB * 1024 + dirp * HH + kt * 32 + qB * 8);
    }
    __syncthreads();
    *(uint4*)((char*)As + rA * 64 + ((qA << 4) ^ ((rA & 3) << 4))) = ra;
#pragma unroll
    for (int it = 0; it < 2; ++it) {
      int c = it * 256 + tid;
      int rB = c >> 2, qB = c & 3;
      *(uint4*)((char*)Bs + rB * 64 + ((qB << 4) ^ ((rB & 3) << 4))) = rb[it];
    }
    __syncthreads();
    const int kb = (lane >> 4) << 4;
    const int rowa = wm * 16 + (lane & 15);
    bf16x8 a = *(const bf16x8*)((const char*)As + rowa * 64 + (kb ^ ((rowa & 3) << 4)));
#pragma unroll
    for (int n = 0; n < 8; ++n) {
      int rowb = n * 16 + (lane & 15);
      bf16x8 b = *(const bf16x8*)((const char*)Bs + rowb * 64 + (kb ^ ((rowb & 3) << 4)));
      acc[n] = __builtin_amdgcn_mfma_f32_16x16x32_bf16(a, b, acc[n], 0, 0, 0);
    }
  }

  const int rbase = (lane >> 4) * 4;
#pragma unroll
  for (int n = 0; n < 8; ++n) {
    int v = n * 16 + (lane & 15);
    float bo = bout[v];
#pragma unroll
    for (int r = 0; r < 4; ++r) {
      int b = bh * 64 + wm * 16 + rbase + r;
      size_t o = ((size_t)b * TT + tp) * VV + v;
      if (mode) (void)unsafeAtomicAdd(&out[o], acc[n][r]);
      else      __hip_atomic_store(&out[o], acc[n][r] + bo, __ATOMIC_RELAXED, AGENT);
    }
  }
}

// ---------------------------------------------------------------------------
// Persistent LSTM layer. 256 WGs = (dir 2)(nb 64)(mh 2), 256 threads.
// WG: M=64 rows (mh half), N=32 (4 gates x 8 units), all weights in LDS.
// hpk: [2 par][2 dir][2 plane hi/lo][128 b][512 bf16] via sc1 (LLC).
// ---------------------------------------------------------------------------
template <int IS_L0, int XS, int KSL>
__global__ __launch_bounds__(256, 1) void lstm_persist(
    const ushort* __restrict__ Wp,    // [128 slices][2*KSL frags][512]
    ushort* __restrict__ hseq,        // [T][B][1024]: L0 writes (plain), L1 x-in
    const int* __restrict__ sent,     // L0: [B][T]
    const ushort* __restrict__ embB,  // L0: [128][256]
    unsigned int* __restrict__ hpk,   // see above (u32 = 2 bf16)
    ushort* __restrict__ ring,        // L1: [2][64][B][512]
    const ushort* __restrict__ WoB,   // L1: [V][1024]
    const float* __restrict__ bout,   // L1: [V]
    float* __restrict__ out,          // L1: [B][T][V]
    const float* __restrict__ bih, const float* __restrict__ bhh,
    unsigned int* __restrict__ bars) {
  const int wg = blockIdx.x;          // (dir<<7) | (nb<<1) | mh
  const int mh = wg & 1;
  const int nb = (wg >> 1) & 63;
  const int dir = wg >> 7;
  const int tid = threadIdx.x;
  const int wm = tid >> 6;
  const int lane = tid & 63;

  __shared__ __align__(16) char smem[KSL * 2048 + 12544];

  // ---- preload full W slice (h frags 0..15, x frags 16..KSL-1) into LDS
  {
    const uint4* wsrc = (const uint4*)(Wp + (size_t)(dir * 64 + nb) * (2 * KSL * 512));
    for (int i = tid; i < KSL * 128; i += 256)
      ((uint4*)smem)[i] = wsrc[i];
  }
  __syncthreads();

  float* exch = (float*)(smem + KSL * 2048);   // [64][33] f32

  const int arow = mh * 64 + wm * 16 + (lane & 15);  // global batch row (A)
  const int ksub = lane >> 4;

  const int ju = nb * 8 + (lane & 7);
  const float biJ = bih[dir * 2048 + ju] + bhh[dir * 2048 + ju];
  const float bfJ = bih[dir * 2048 + 512 + ju] + bhh[dir * 2048 + 512 + ju];
  const float bgJ = bih[dir * 2048 + 1024 + ju] + bhh[dir * 2048 + 1024 + ju];
  const float boJ = bih[dir * 2048 + 1536 + ju] + bhh[dir * 2048 + 1536 + ju];
  const float bias0 = (lane & 8) ? bfJ : biJ;
  const float bias1 = (lane & 8) ? boJ : bgJ;

  float cst0 = 0.f, cst1 = 0.f;        // c for (row tid>>2, units 2q, 2q+1)
  unsigned int* stepslot = bars;        // [256]
  unsigned int* projslot = bars + 256;  // [256]

  f32x4 acc0, acc1;

  const unsigned long long* hpk64 = (const unsigned long long*)hpk;

  // x-part: acc = bias + x(t) @ Wih^T  (XS k-steps; W frags 16..)
  auto x_phase = [&](int t) {
    acc0 = (f32x4){bias0, bias0, bias0, bias0};
    acc1 = (f32x4){bias1, bias1, bias1, bias1};
    const ushort* xr;
    if constexpr (IS_L0) xr = embB + sent[arow * TT + t] * 256 + ksub * 8;
    else                 xr = hseq + ((size_t)t * BB + arow) * 1024 + ksub * 8;
    uint4 xa[XS];
#pragma unroll
    for (int i = 0; i < XS; ++i) xa[i] = *(const uint4*)(xr + i * 32);
#pragma unroll
    for (int i = 0; i < XS; ++i) {
      bf16x8 b0 = *(const bf16x8*)(smem + (16 + i) * 2048 + (lane << 4));
      bf16x8 b1 = *(const bf16x8*)(smem + (16 + i) * 2048 + 1024 + (lane << 4));
      acc0 = __builtin_amdgcn_mfma_f32_16x16x32_bf16(bc8(xa[i]), b0, acc0, 0, 0, 0);
      acc1 = __builtin_amdgcn_mfma_f32_16x16x32_bf16(bc8(xa[i]), b1, acc1, 0, 0, 0);
    }
  };

  // h-part: acc += Whh*(hi + lo); all 64 u64 loads batched up front (sc1/LLC)
  auto h_phase = [&](int par) {
    const unsigned long long* hb = hpk64 + (size_t)par * 65536 + (size_t)dir * 32768 +
                                   (size_t)arow * 128 + ksub * 2;
    unsigned long long ah[64];
#pragma unroll
    for (int ks = 0; ks < 16; ++ks) {
      ah[2 * ks]          = __hip_atomic_load(hb + ks * 8,             __ATOMIC_RELAXED, AGENT);
      ah[2 * ks + 1]      = __hip_atomic_load(hb + ks * 8 + 1,         __ATOMIC_RELAXED, AGENT);
      ah[32 + 2 * ks]     = __hip_atomic_load(hb + 16384 + ks * 8,     __ATOMIC_RELAXED, AGENT);
      ah[32 + 2 * ks + 1] = __hip_atomic_load(hb + 16384 + ks * 8 + 1, __ATOMIC_RELAXED, AGENT);
    }
#pragma unroll
    for (int ks = 0; ks < 16; ++ks) {
      uint4 uhi = make_uint4((uint32_t)ah[2 * ks], (uint32_t)(ah[2 * ks] >> 32),
                             (uint32_t)ah[2 * ks + 1], (uint32_t)(ah[2 * ks + 1] >> 32));
      uint4 ulo = make_uint4((uint32_t)ah[32 + 2 * ks], (uint32_t)(ah[32 + 2 * ks] >> 32),
                             (uint32_t)ah[32 + 2 * ks + 1], (uint32_t)(ah[32 + 2 * ks + 1] >> 32));
      bf16x8 b0 = *(const bf16x8*)(smem + ks * 2048 + (lane << 4));
      bf16x8 b1 = *(const bf16x8*)(smem + ks * 2048 + 1024 + (lane << 4));
      acc0 = __builtin_amdgcn_mfma_f32_16x16x32_bf16(bc8(uhi), b0, acc0, 0, 0, 0);
      acc1 = __builtin_amdgcn_mfma_f32_16x16x32_bf16(bc8(uhi), b1, acc1, 0, 0, 0);
      acc0 = __builtin_amdgcn_mfma_f32_16x16x32_bf16(bc8(ulo), b0, acc0, 0, 0, 0);
      acc1 = __builtin_amdgcn_mfma_f32_16x16x32_bf16(bc8(ulo), b1, acc1, 0, 0, 0);
    }
  };

  // prologue: x-part for step 0
  x_phase(dir ? TT - 1 : 0);
  unsigned int pcount = 0;

  for (int s = 0; s < TT; ++s) {
    const int t = dir ? (TT - 1 - s) : s;

    // ---- wait: own-dir 128 slots >= s (each thread watches one slot)
    if (tid < 128) {
      while (__hip_atomic_load(&stepslot[dir * 128 + tid], __ATOMIC_RELAXED, AGENT) <
             (unsigned)s)
        __builtin_amdgcn_s_sleep(1);
    }
    __syncthreads();

    h_phase(s & 1);

    // ---- gate exchange through LDS [64][33] f32
    {
      const int rb4 = (lane >> 4) * 4;
#pragma unroll
      for (int r = 0; r < 4; ++r) {
        int lr = wm * 16 + rb4 + r;
        exch[lr * 33 + (lane & 15)]      = acc0[r];
        exch[lr * 33 + 16 + (lane & 15)] = acc1[r];
      }
    }
    __syncthreads();

    // ---- epilogue: thread -> (lr = tid>>2, q = tid&3) owns units 2q, 2q+1
    {
      const int lr = tid >> 2;
      const int q = tid & 3;
      ushort hh[2], hl[2];
#pragma unroll
      for (int i = 0; i < 2; ++i) {
        const int u = q * 2 + i;
        float gi = exch[lr * 33 + u];
        float gf = exch[lr * 33 + 8 + u];
        float gg = exch[lr * 33 + 16 + u];
        float go = exch[lr * 33 + 24 + u];
        float si = sigm(gi), sf = sigm(gf), tg = tanh_f(gg), so = sigm(go);
        float c = sf * (i ? cst1 : cst0) + si * tg;
        (i ? cst1 : cst0) = c;
        float h = so * tanh_f(c);
        hh[i] = f2bf(h);
        hl[i] = f2bf(h - bf2f(hh[i]));
      }
      const int b = mh * 64 + lr;
      const uint32_t vhi = (uint32_t)hh[0] | ((uint32_t)hh[1] << 16);
      const uint32_t vlo = (uint32_t)hl[0] | ((uint32_t)hl[1] << 16);
      unsigned int* hw = hpk + (size_t)((s & 1) ^ 1) * 131072 + (size_t)dir * 65536;
      __hip_atomic_store(hw + (size_t)b * 256 + nb * 4 + q, vhi, __ATOMIC_RELAXED, AGENT);
      __hip_atomic_store(hw + 32768 + (size_t)b * 256 + nb * 4 + q, vlo,
                         __ATOMIC_RELAXED, AGENT);
      if constexpr (IS_L0) {
        *((uint32_t*)hseq + ((size_t)t * BB + b) * 512 + dir * 256 + nb * 4 + q) = vhi;
      } else {
        __hip_atomic_store((unsigned int*)ring +
                               ((size_t)(dir * 64 + (t & 63)) * BB + b) * 256 + nb * 4 + q,
                           vhi, __ATOMIC_RELAXED, AGENT);
      }
    }

    __syncthreads();  // drain stores (vmcnt 0) + protect exch
    if (tid == 0)
      __hip_atomic_store(&stepslot[wg], (unsigned)(s + 1), __ATOMIC_RELAXED, AGENT);

    // x-part for step s+1 in the wait shadow
    if (s + 1 < TT) x_phase(dir ? (TT - 2 - s) : (s + 1));

    if constexpr (!IS_L0) {
      if ((s & 63) == 63) {
        // all 256 WGs published this chunk; ACQUIRE (L2 inv) for plain ring reads
        {
          const unsigned tgt = (unsigned)(s + 1);
          while (__hip_atomic_load(&stepslot[tid], __ATOMIC_RELAXED, AGENT) < tgt)
            __builtin_amdgcn_s_sleep(1);
        }
        __syncthreads();
        if (tid == 0) (void)__hip_atomic_load(&stepslot[0], __ATOMIC_ACQUIRE, AGENT);
        __syncthreads();
        proj_body(s >> 6, wg & 63, (wg >> 6) & 1, wg >> 7, tid, ring, WoB, bout, out,
                  smem + KSL * 2048);
        __syncthreads();  // proj loads drained
        ++pcount;
        if (tid == 0)
          __hip_atomic_store(&projslot[wg], pcount, __ATOMIC_RELAXED, AGENT);
        while (__hip_atomic_load(&projslot[tid], __ATOMIC_RELAXED, AGENT) < pcount)
          __builtin_amdgcn_s_sleep(1);
        __syncthreads();
      }
    }
  }
}

// ---------------------------------------------------------------------------
extern "C" void kernel_launch(void* const* d_in, const int* in_sizes, int n_in,
                              void* d_out, int out_size, void* d_ws, size_t ws_size,
                              hipStream_t stream) {
  const int* sent = (const int*)d_in[0];
  const float* emb = (const float*)d_in[1];
  const float* Wih0 = (const float*)d_in[2];
  const float* Whh0 = (const float*)d_in[3];
  const float* bih0 = (const float*)d_in[4];
  const float* bhh0 = (const float*)d_in[5];
  const float* Wih1 = (const float*)d_in[6];
  const float* Whh1 = (const float*)d_in[7];
  const float* bih1 = (const float*)d_in[8];
  const float* bhh1 = (const float*)d_in[9];
  const float* Wout = (const float*)d_in[10];
  const float* bout = (const float*)d_in[11];
  float* out = (float*)d_out;

  // ws layout (bytes); total 171,247,616
  const size_t NEED = 171247616;
  if (ws_size < NEED) {
    report_ws<<<(out_size + 255) / 256, 256, 0, stream>>>(out, out_size,
                                                          (float)(ws_size >> 20));
    return;
  }
  char* ws = (char*)d_ws;
  ushort* h0   = (ushort*)(ws + 0);                 // 134,217,728  [T][B][1024]
  ushort* Wp0  = (ushort*)(ws + 134217728);         //   6,291,456  KSL=24
  ushort* Wp1  = (ushort*)(ws + 140509184);         //  12,582,912  KSL=48
  ushort* WoB  = (ushort*)(ws + 153092096);         //     262,144
  ushort* embB = (ushort*)(ws + 153354240);         //      65,536
  unsigned int* hpk = (unsigned int*)(ws + 153419776); // 1,048,576
  ushort* ring = (ushort*)(ws + 154468352);         //  16,777,216  [2][64][B][512]
  unsigned int* bars = (unsigned int*)(ws + 171245568);  // 2048B (512 u32)

  pack_emb<<<128, 256, 0, stream>>>(emb, embB);
  pack_w<<<12288, 256, 0, stream>>>(Whh0, Wih0, Wp0, 24, 256);
  pack_w<<<24576, 256, 0, stream>>>(Whh1, Wih1, Wp1, 48, 1024);
  pack_wout<<<512, 256, 0, stream>>>(Wout, WoB);

  // layer 0 (persistent, 256 WGs)
  zero_h<<<256, 256, 0, stream>>>(hpk, bars);
  lstm_persist<1, 8, 24><<<256, 256, 0, stream>>>(
      Wp0, h0, sent, embB, hpk, ring, WoB, bout, out, bih0, bhh0, bars);

  // layer 1 (persistent, proj folded in)
  zero_h<<<256, 256, 0, stream>>>(hpk, bars);
  lstm_persist<0, 32, 48><<<256, 256, 0, stream>>>(
      Wp1, h0, sent, embB, hpk, ring, WoB, bout, out, bih1, bhh1, bars);
}

// Round 10
// 11022.269 us; speedup vs baseline: 2.9962x; 1.0789x over previous
//
#include <hip/hip_runtime.h>
#include <stdint.h>

// ---------------------------------------------------------------------------
// 2-layer BiLSTM LM: emb -> BiLSTM(E=256->H=512) -> BiLSTM(1024->512) -> proj
// V=128 E=256 H=512 B=128 T=512.
//
// Round 10 (r9 post-mortem: 32MB/step of sc1 LLC-direct h reads -- 64x
// broadcast amplification with no cache -- at ~2.3TB/s = ~7us/step dominated
// both layers; FETCH_SIZE didn't even see it, confirming L2 bypass):
//  - h reads -> PLAIN uint4 loads served by L2 (line fetched once per XCD
//    from LLC, then 34.5TB/s broadcast to 32 WGs/XCD).
//  - per-step consumer ACQUIRE (L1+L2 inv) after the spin -- safe now
//    because ALL weights are LDS-resident (r9) and producers write sc1
//    (write-through => L2 never dirty => inv never discards data).
//    Pattern (sc1 store -> ACQUIRE -> plain load) validated by proj r7-r9.
//  - L0 hseq stores -> sc1 (plain dirty lines would be DISCARDED by inv).
//  - everything else unchanged from r9 (LDS W, 256 WGs, slot barrier,
//    x_phase in shadow, proj chunks, epilogue ownership).
//
// Numerics (validated r1..r9, absmax 1.95e-3): bf16 MFMA fp32-accum; c f32;
// h carried as hi/lo bf16 planes; gates = Whh*(hi+lo) + Wih*x + b.
// ---------------------------------------------------------------------------

#define TT 512
#define BB 128
#define HH 512
#define VV 128
#define AGENT __HIP_MEMORY_SCOPE_AGENT

typedef __attribute__((ext_vector_type(8))) short bf16x8;
typedef __attribute__((ext_vector_type(4))) float f32x4;

__device__ __forceinline__ ushort f2bf(float f) {
  uint32_t u = __builtin_bit_cast(uint32_t, f);
  u += 0x7FFFu + ((u >> 16) & 1u);
  return (ushort)(u >> 16);
}
__device__ __forceinline__ float bf2f(ushort h) {
  uint32_t u = ((uint32_t)h) << 16;
  return __builtin_bit_cast(float, u);
}
__device__ __forceinline__ float sigm(float x) { return 1.f / (1.f + __expf(-x)); }
__device__ __forceinline__ float tanh_f(float x) { return 1.f - 2.f / (__expf(2.f * x) + 1.f); }
__device__ __forceinline__ bf16x8 bc8(uint4 u) { return __builtin_bit_cast(bf16x8, u); }

__global__ __launch_bounds__(256) void report_ws(float* __restrict__ out, int n, float val) {
  int i = blockIdx.x * 256 + threadIdx.x;
  if (i < n) out[i] = val;
}

__global__ __launch_bounds__(256) void pack_emb(const float* __restrict__ emb,
                                                ushort* __restrict__ embB) {
  int i = blockIdx.x * 256 + threadIdx.x;  // 32768
  embB[i] = f2bf(emb[i]);
}

// Frag-packed W, NO dup. Slice (d, nb) = 2*KSL frags of 1KB.
// frag f = kslg*2 + n2; elem (l,e): rloc = n2*16 + (l&15);
// grow = (rloc>>3)*512 + nb*8 + (rloc&7); k = kslg*32 + (l>>4)*8 + e.
// k<512 -> Whh[d][grow][k]; else Wih[d][grow][k-512].
__global__ __launch_bounds__(256) void pack_w(const float* __restrict__ Whh,
                                              const float* __restrict__ Wih,
                                              ushort* __restrict__ Wp,
                                              int KSL, int Ein) {
  size_t idx = (size_t)blockIdx.x * 256 + threadIdx.x;
  size_t total = (size_t)128 * 2 * KSL * 512;
  if (idx >= total) return;
  int e = (int)(idx & 7);
  int l = (int)((idx >> 3) & 63);
  int f = (int)((idx >> 9) % (size_t)(2 * KSL));
  int sl = (int)(idx / ((size_t)1024 * KSL));
  int nb = sl & 63, d = sl >> 6;
  int n2 = f & 1, kslg = f >> 1;
  int rloc = n2 * 16 + (l & 15);
  int grow = (rloc >> 3) * 512 + nb * 8 + (rloc & 7);
  int k = kslg * 32 + (l >> 4) * 8 + e;
  float val;
  if (k < 512) val = Whh[((size_t)d * 2048 + grow) * 512 + k];
  else         val = Wih[((size_t)d * 2048 + grow) * Ein + (k - 512)];
  Wp[idx] = f2bf(val);
}

__global__ __launch_bounds__(256) void pack_wout(const float* __restrict__ Wo,
                                                 ushort* __restrict__ WoB) {
  int i = blockIdx.x * 256 + threadIdx.x;  // 131072
  WoB[i] = f2bf(Wo[i]);
}

// zero hpk (1MB = 65536 uint4) + barrier slots (512 u32)
__global__ __launch_bounds__(256) void zero_h(unsigned int* __restrict__ hpk,
                                              unsigned int* __restrict__ bars) {
  int i = blockIdx.x * 256 + threadIdx.x;  // grid 256
  ((uint4*)hpk)[i] = make_uint4(0, 0, 0, 0);
  if (i < 512) bars[i] = 0;
}

// ---------------------------------------------------------------------------
// Projection chunk: WG handles t = base(dirp,k)+slot, rows bh*64..+63,
// all 128 v, K = 512 (one dir's half). k<=3: write (+bout); k>=4: atomic add.
// ---------------------------------------------------------------------------
__device__ void proj_body(int k, int slot, int dirp, int bh, int tid,
                          const ushort* __restrict__ ring,
                          const ushort* __restrict__ WoB,
                          const float* __restrict__ bout,
                          float* __restrict__ out, char* shm) {
  const int tp = (dirp ? (448 - 64 * k) : (64 * k)) + slot;
  const int mode = (k >= 4);
  ushort* As = (ushort*)shm;            // [64][32] swizzled 64B rows
  ushort* Bs = (ushort*)(shm + 4096);   // [128][32] swizzled
  const int wm = tid >> 6;
  const int lane = tid & 63;

  f32x4 acc[8] = {};

  for (int kt = 0; kt < 16; ++kt) {     // K = 512
    const int rA = tid >> 2, qA = tid & 3;
    uint4 ra = *(const uint4*)(ring + ((size_t)(dirp * 64 + slot) * BB + bh * 64 + rA) * HH +
                               kt * 32 + qA * 8);
    uint4 rb[2];
#pragma unroll
    for (int it = 0; it < 2; ++it) {
      int c = it * 256 + tid;
      int rB = c >> 2, qB = c & 3;
      rb[it] = *(const uint4*)(WoB + (size_t)rB * 1024 + dirp * HH + kt * 32 + qB * 8);
    }
    __syncthreads();
    *(uint4*)((char*)As + rA * 64 + ((qA << 4) ^ ((rA & 3) << 4))) = ra;
#pragma unroll
    for (int it = 0; it < 2; ++it) {
      int c = it * 256 + tid;
      int rB = c >> 2, qB = c & 3;
      *(uint4*)((char*)Bs + rB * 64 + ((qB << 4) ^ ((rB & 3) << 4))) = rb[it];
    }
    __syncthreads();
    const int kb = (lane >> 4) << 4;
    const int rowa = wm * 16 + (lane & 15);
    bf16x8 a = *(const bf16x8*)((const char*)As + rowa * 64 + (kb ^ ((rowa & 3) << 4)));
#pragma unroll
    for (int n = 0; n < 8; ++n) {
      int rowb = n * 16 + (lane & 15);
      bf16x8 b = *(const bf16x8*)((const char*)Bs + rowb * 64 + (kb ^ ((rowb & 3) << 4)));
      acc[n] = __builtin_amdgcn_mfma_f32_16x16x32_bf16(a, b, acc[n], 0, 0, 0);
    }
  }

  const int rbase = (lane >> 4) * 4;
#pragma unroll
  for (int n = 0; n < 8; ++n) {
    int v = n * 16 + (lane & 15);
    float bo = bout[v];
#pragma unroll
    for (int r = 0; r < 4; ++r) {
      int b = bh * 64 + wm * 16 + rbase + r;
      size_t o = ((size_t)b * TT + tp) * VV + v;
      if (mode) (void)unsafeAtomicAdd(&out[o], acc[n][r]);
      else      __hip_atomic_store(&out[o], acc[n][r] + bo, __ATOMIC_RELAXED, AGENT);
    }
  }
}

// ---------------------------------------------------------------------------
// Persistent LSTM layer. 256 WGs = (dir 2)(nb 64)(mh 2), 256 threads.
// WG: M=64 rows (mh half), N=32 (4 gates x 8 units), all weights in LDS.
// hpk: [2 par][2 dir][2 plane hi/lo][128 b][512 bf16]; written sc1 (L2 stays
// clean), read PLAIN via L2 after the per-step ACQUIRE inv.
// ---------------------------------------------------------------------------
template <int IS_L0, int XS, int KSL>
__global__ __launch_bounds__(256, 1) void lstm_persist(
    const ushort* __restrict__ Wp,    // [128 slices][2*KSL frags][512]
    ushort* __restrict__ hseq,        // [T][B][1024]: L0 writes (sc1), L1 x-in
    const int* __restrict__ sent,     // L0: [B][T]
    const ushort* __restrict__ embB,  // L0: [128][256]
    unsigned int* __restrict__ hpk,   // see above (u32 = 2 bf16)
    ushort* __restrict__ ring,        // L1: [2][64][B][512]
    const ushort* __restrict__ WoB,   // L1: [V][1024]
    const float* __restrict__ bout,   // L1: [V]
    float* __restrict__ out,          // L1: [B][T][V]
    const float* __restrict__ bih, const float* __restrict__ bhh,
    unsigned int* __restrict__ bars) {
  const int wg = blockIdx.x;          // (dir<<7) | (nb<<1) | mh
  const int mh = wg & 1;
  const int nb = (wg >> 1) & 63;
  const int dir = wg >> 7;
  const int tid = threadIdx.x;
  const int wm = tid >> 6;
  const int lane = tid & 63;

  __shared__ __align__(16) char smem[KSL * 2048 + 12544];

  // ---- preload full W slice (h frags 0..15, x frags 16..KSL-1) into LDS
  {
    const uint4* wsrc = (const uint4*)(Wp + (size_t)(dir * 64 + nb) * (2 * KSL * 512));
    for (int i = tid; i < KSL * 128; i += 256)
      ((uint4*)smem)[i] = wsrc[i];
  }
  __syncthreads();

  float* exch = (float*)(smem + KSL * 2048);   // [64][33] f32

  const int arow = mh * 64 + wm * 16 + (lane & 15);  // global batch row (A)
  const int ksub = lane >> 4;

  const int ju = nb * 8 + (lane & 7);
  const float biJ = bih[dir * 2048 + ju] + bhh[dir * 2048 + ju];
  const float bfJ = bih[dir * 2048 + 512 + ju] + bhh[dir * 2048 + 512 + ju];
  const float bgJ = bih[dir * 2048 + 1024 + ju] + bhh[dir * 2048 + 1024 + ju];
  const float boJ = bih[dir * 2048 + 1536 + ju] + bhh[dir * 2048 + 1536 + ju];
  const float bias0 = (lane & 8) ? bfJ : biJ;
  const float bias1 = (lane & 8) ? boJ : bgJ;

  float cst0 = 0.f, cst1 = 0.f;        // c for (row tid>>2, units 2q, 2q+1)
  unsigned int* stepslot = bars;        // [256]
  unsigned int* projslot = bars + 256;  // [256]

  f32x4 acc0, acc1;

  // x-part: acc = bias + x(t) @ Wih^T  (XS k-steps; W frags 16..)
  auto x_phase = [&](int t) {
    acc0 = (f32x4){bias0, bias0, bias0, bias0};
    acc1 = (f32x4){bias1, bias1, bias1, bias1};
    const ushort* xr;
    if constexpr (IS_L0) xr = embB + sent[arow * TT + t] * 256 + ksub * 8;
    else                 xr = hseq + ((size_t)t * BB + arow) * 1024 + ksub * 8;
    uint4 xa[XS];
#pragma unroll
    for (int i = 0; i < XS; ++i) xa[i] = *(const uint4*)(xr + i * 32);
#pragma unroll
    for (int i = 0; i < XS; ++i) {
      bf16x8 b0 = *(const bf16x8*)(smem + (16 + i) * 2048 + (lane << 4));
      bf16x8 b1 = *(const bf16x8*)(smem + (16 + i) * 2048 + 1024 + (lane << 4));
      acc0 = __builtin_amdgcn_mfma_f32_16x16x32_bf16(bc8(xa[i]), b0, acc0, 0, 0, 0);
      acc1 = __builtin_amdgcn_mfma_f32_16x16x32_bf16(bc8(xa[i]), b1, acc1, 0, 0, 0);
    }
  };

  // h-part: acc += Whh*(hi + lo). PLAIN uint4 loads (L2-served, post-inv),
  // all batched before consumption.
  auto h_phase = [&](int par) {
    const uint4* hb = (const uint4*)hpk + (size_t)par * 32768 + (size_t)dir * 16384 +
                      (size_t)arow * 64 + ksub;
    uint4 ahi[16], alo[16];
#pragma unroll
    for (int ks = 0; ks < 16; ++ks) ahi[ks] = hb[ks * 4];
#pragma unroll
    for (int ks = 0; ks < 16; ++ks) alo[ks] = hb[8192 + ks * 4];
#pragma unroll
    for (int ks = 0; ks < 16; ++ks) {
      bf16x8 b0 = *(const bf16x8*)(smem + ks * 2048 + (lane << 4));
      bf16x8 b1 = *(const bf16x8*)(smem + ks * 2048 + 1024 + (lane << 4));
      acc0 = __builtin_amdgcn_mfma_f32_16x16x32_bf16(bc8(ahi[ks]), b0, acc0, 0, 0, 0);
      acc1 = __builtin_amdgcn_mfma_f32_16x16x32_bf16(bc8(ahi[ks]), b1, acc1, 0, 0, 0);
      acc0 = __builtin_amdgcn_mfma_f32_16x16x32_bf16(bc8(alo[ks]), b0, acc0, 0, 0, 0);
      acc1 = __builtin_amdgcn_mfma_f32_16x16x32_bf16(bc8(alo[ks]), b1, acc1, 0, 0, 0);
    }
  };

  // prologue: x-part for step 0
  x_phase(dir ? TT - 1 : 0);
  unsigned int pcount = 0;

  for (int s = 0; s < TT; ++s) {
    const int t = dir ? (TT - 1 - s) : s;

    // ---- wait: own-dir 128 slots >= s; then ACQUIRE (L1+L2 inv) so plain
    //      h loads see the sc1-published data. L2 is always clean (all
    //      global writes in this kernel are sc1/atomic) => inv loses nothing.
    if (tid < 128) {
      while (__hip_atomic_load(&stepslot[dir * 128 + tid], __ATOMIC_RELAXED, AGENT) <
             (unsigned)s)
        __builtin_amdgcn_s_sleep(1);
    }
    __syncthreads();
    if (tid == 0)
      (void)__hip_atomic_load(&stepslot[wg], __ATOMIC_ACQUIRE, AGENT);
    __syncthreads();

    h_phase(s & 1);

    // ---- gate exchange through LDS [64][33] f32
    {
      const int rb4 = (lane >> 4) * 4;
#pragma unroll
      for (int r = 0; r < 4; ++r) {
        int lr = wm * 16 + rb4 + r;
        exch[lr * 33 + (lane & 15)]      = acc0[r];
        exch[lr * 33 + 16 + (lane & 15)] = acc1[r];
      }
    }
    __syncthreads();

    // ---- epilogue: thread -> (lr = tid>>2, q = tid&3) owns units 2q, 2q+1
    {
      const int lr = tid >> 2;
      const int q = tid & 3;
      ushort hh[2], hl[2];
#pragma unroll
      for (int i = 0; i < 2; ++i) {
        const int u = q * 2 + i;
        float gi = exch[lr * 33 + u];
        float gf = exch[lr * 33 + 8 + u];
        float gg = exch[lr * 33 + 16 + u];
        float go = exch[lr * 33 + 24 + u];
        float si = sigm(gi), sf = sigm(gf), tg = tanh_f(gg), so = sigm(go);
        float c = sf * (i ? cst1 : cst0) + si * tg;
        (i ? cst1 : cst0) = c;
        float h = so * tanh_f(c);
        hh[i] = f2bf(h);
        hl[i] = f2bf(h - bf2f(hh[i]));
      }
      const int b = mh * 64 + lr;
      const uint32_t vhi = (uint32_t)hh[0] | ((uint32_t)hh[1] << 16);
      const uint32_t vlo = (uint32_t)hl[0] | ((uint32_t)hl[1] << 16);
      unsigned int* hw = hpk + (size_t)((s & 1) ^ 1) * 131072 + (size_t)dir * 65536;
      __hip_atomic_store(hw + (size_t)b * 256 + nb * 4 + q, vhi, __ATOMIC_RELAXED, AGENT);
      __hip_atomic_store(hw + 32768 + (size_t)b * 256 + nb * 4 + q, vlo,
                         __ATOMIC_RELAXED, AGENT);
      if constexpr (IS_L0) {
        // sc1 (write-through): plain dirty lines would be discarded by the
        // per-step inv of other WGs' ACQUIREs in THIS kernel.
        __hip_atomic_store((unsigned int*)hseq + ((size_t)t * BB + b) * 512 +
                               dir * 256 + nb * 4 + q,
                           vhi, __ATOMIC_RELAXED, AGENT);
      } else {
        __hip_atomic_store((unsigned int*)ring +
                               ((size_t)(dir * 64 + (t & 63)) * BB + b) * 256 + nb * 4 + q,
                           vhi, __ATOMIC_RELAXED, AGENT);
      }
    }

    __syncthreads();  // drain stores (vmcnt 0) + protect exch
    if (tid == 0)
      __hip_atomic_store(&stepslot[wg], (unsigned)(s + 1), __ATOMIC_RELAXED, AGENT);

    // x-part for step s+1 in the wait shadow
    if (s + 1 < TT) x_phase(dir ? (TT - 2 - s) : (s + 1));

    if constexpr (!IS_L0) {
      if ((s & 63) == 63) {
        // all 256 WGs published this chunk; ACQUIRE (L2 inv) for plain ring reads
        {
          const unsigned tgt = (unsigned)(s + 1);
          while (__hip_atomic_load(&stepslot[tid], __ATOMIC_RELAXED, AGENT) < tgt)
            __builtin_amdgcn_s_sleep(1);
        }
        __syncthreads();
        if (tid == 0) (void)__hip_atomic_load(&stepslot[0], __ATOMIC_ACQUIRE, AGENT);
        __syncthreads();
        proj_body(s >> 6, wg & 63, (wg >> 6) & 1, wg >> 7, tid, ring, WoB, bout, out,
                  smem + KSL * 2048);
        __syncthreads();  // proj loads drained
        ++pcount;
        if (tid == 0)
          __hip_atomic_store(&projslot[wg], pcount, __ATOMIC_RELAXED, AGENT);
        while (__hip_atomic_load(&projslot[tid], __ATOMIC_RELAXED, AGENT) < pcount)
          __builtin_amdgcn_s_sleep(1);
        __syncthreads();
      }
    }
  }
}

// ---------------------------------------------------------------------------
extern "C" void kernel_launch(void* const* d_in, const int* in_sizes, int n_in,
                              void* d_out, int out_size, void* d_ws, size_t ws_size,
                              hipStream_t stream) {
  const int* sent = (const int*)d_in[0];
  const float* emb = (const float*)d_in[1];
  const float* Wih0 = (const float*)d_in[2];
  const float* Whh0 = (const float*)d_in[3];
  const float* bih0 = (const float*)d_in[4];
  const float* bhh0 = (const float*)d_in[5];
  const float* Wih1 = (const float*)d_in[6];
  const float* Whh1 = (const float*)d_in[7];
  const float* bih1 = (const float*)d_in[8];
  const float* bhh1 = (const float*)d_in[9];
  const float* Wout = (const float*)d_in[10];
  const float* bout = (const float*)d_in[11];
  float* out = (float*)d_out;

  // ws layout (bytes); total 171,247,616
  const size_t NEED = 171247616;
  if (ws_size < NEED) {
    report_ws<<<(out_size + 255) / 256, 256, 0, stream>>>(out, out_size,
                                                          (float)(ws_size >> 20));
    return;
  }
  char* ws = (char*)d_ws;
  ushort* h0   = (ushort*)(ws + 0);                 // 134,217,728  [T][B][1024]
  ushort* Wp0  = (ushort*)(ws + 134217728);         //   6,291,456  KSL=24
  ushort* Wp1  = (ushort*)(ws + 140509184);         //  12,582,912  KSL=48
  ushort* WoB  = (ushort*)(ws + 153092096);         //     262,144
  ushort* embB = (ushort*)(ws + 153354240);         //      65,536
  unsigned int* hpk = (unsigned int*)(ws + 153419776); // 1,048,576
  ushort* ring = (ushort*)(ws + 154468352);         //  16,777,216  [2][64][B][512]
  unsigned int* bars = (unsigned int*)(ws + 171245568);  // 2048B (512 u32)

  pack_emb<<<128, 256, 0, stream>>>(emb, embB);
  pack_w<<<12288, 256, 0, stream>>>(Whh0, Wih0, Wp0, 24, 256);
  pack_w<<<24576, 256, 0, stream>>>(Whh1, Wih1, Wp1, 48, 1024);
  pack_wout<<<512, 256, 0, stream>>>(Wout, WoB);

  // layer 0 (persistent, 256 WGs)
  zero_h<<<256, 256, 0, stream>>>(hpk, bars);
  lstm_persist<1, 8, 24><<<256, 256, 0, stream>>>(
      Wp0, h0, sent, embB, hpk, ring, WoB, bout, out, bih0, bhh0, bars);

  // layer 1 (persistent, proj folded in)
  zero_h<<<256, 256, 0, stream>>>(hpk, bars);
  lstm_persist<0, 32, 48><<<256, 256, 0, stream>>>(
      Wp1, h0, sent, embB, hpk, ring, WoB, bout, out, bih1, bhh1, bars);
}